// Round 12
// baseline (1339.277 us; speedup 1.0000x reference)
//
#include <hip/hip_runtime.h>
#include <hip/hip_bf16.h>
#include <type_traits>

#define NN 50000     // nodes per side (users == items == 50000)
#define NE 600000    // edges per relation
#define HF 256       // hidden features

typedef float f32x4 __attribute__((ext_vector_type(4)));
typedef _Float16 f16x8 __attribute__((ext_vector_type(8)));
typedef _Float16 f16x4 __attribute__((ext_vector_type(4)));

// ---------- fp32 -> fp16 convert, both inputs in one dispatch ----------
__global__ __launch_bounds__(256) void k_tofp16_2(const float* __restrict__ A,
                                                  const float* __restrict__ B,
                                                  _Float16* __restrict__ OA,
                                                  _Float16* __restrict__ OB, int n4) {
  int i = blockIdx.x * 256 + threadIdx.x;
  const float* X = (i < n4) ? A : B;
  _Float16* Y = (i < n4) ? OA : OB;
  int j = (i < n4) ? i : i - n4;
  if (j < n4) {
    float4 v = reinterpret_cast<const float4*>(X)[j];
    f16x4 o = {(_Float16)v.x, (_Float16)v.y, (_Float16)v.z, (_Float16)v.w};
    reinterpret_cast<f16x4*>(Y)[j] = o;
  }
}

// ---------- all 8 W[K][256] -> Wt[256][K] transposes in one dispatch ----------
struct TArgs {
  const float* W[8];
  _Float16* dst[8];
  int K[8];
  int cum[9];
};
__global__ __launch_bounds__(256) void k_transpose_all(TArgs t) {
  int idx = blockIdx.x * 256 + threadIdx.x;
#pragma unroll
  for (int s = 0; s < 8; ++s) {
    if (idx >= t.cum[s] && idx < t.cum[s + 1]) {
      int local = idx - t.cum[s];
      int K = t.K[s];
      int k = local >> 8;
      int n = local & 255;
      t.dst[s][(size_t)n * K + k] = (_Float16)t.W[s][local];
    }
  }
}

// ---------- all W.ar attn tables, fp16 [16][256]-padded, in one dispatch ----------
__global__ __launch_bounds__(256) void k_makeattn_all(
    const float* __restrict__ W1, const float* __restrict__ W2,
    const float* __restrict__ W3, const float* __restrict__ W4,
    const float* __restrict__ ar1, const float* __restrict__ ar2,
    const float* __restrict__ ar3, const float* __restrict__ ar4,
    _Float16* __restrict__ wart) {   // [8][16][256] fp16, cols 4..15 stay zero
  int idx = blockIdx.x * 256 + threadIdx.x;
  if (idx >= 8 * 256 * 4) return;
  int h = idx & 3;
  int k = (idx >> 2) & 255;
  int s = idx >> 10;  // l*2+r
  int l = s >> 1, r = s & 1;
  int K = (l == 0) ? 128 : 256;
  if (k >= K) return;
  const float* W = (l == 0 ? W1 : l == 1 ? W2 : l == 2 ? W3 : W4) + (size_t)r * K * 256;
  const float* a = (l == 0 ? ar1 : l == 1 ? ar2 : l == 2 ? ar3 : ar4) + r * 256 + h * 64;
  const float* wrow = W + (size_t)k * 256 + h * 64;
  float sum = 0.f;
#pragma unroll 8
  for (int d = 0; d < 64; ++d) sum += wrow[d] * a[d];
  wart[(size_t)s * 4096 + h * 256 + k] = (_Float16)sum;
}

// ---------- GEMM v5b: 64x256 tile, LDS-staged A (swizzled) dbuf, fused el + er(MFMA) ----------
struct GArgs {
  const _Float16* A0; const _Float16* A1;     // post-BN activations
  const _Float16* Wt0; const _Float16* Wt1;
  _Float16* Z0; _Float16* Z1;
  const float* al0; const float* al1;
  float* EL0; float* EL1;
  const _Float16* wart_s0; const _Float16* wart_s1;  // [16][256] fp16 W.ar tables
  float* ER_s0; float* ER_s1;                 // side0 -> ER1, side1 -> ER0
  int M, K;
};

__global__ __launch_bounds__(256) void k_gemm5(GArgs ga) {
  __shared__ _Float16 As[2][64 * 64];    // 2 x 8 KB double buffer
  const int nrow = (NN + 63) / 64;       // 782
  int side = blockIdx.x >= nrow;
  int bid = side ? blockIdx.x - nrow : blockIdx.x;
  const _Float16* A = side ? ga.A1 : ga.A0;
  const _Float16* Wt = side ? ga.Wt1 : ga.Wt0;
  _Float16* Z = side ? ga.Z1 : ga.Z0;
  const float* al = side ? ga.al1 : ga.al0;
  float* EL = side ? ga.EL1 : ga.EL0;
  const _Float16* wart = side ? ga.wart_s1 : ga.wart_s0;
  float* ER = side ? ga.ER_s1 : ga.ER_s0;
  const int K = ga.K, M = ga.M;
  int row0 = bid * 64;
  int wave = threadIdx.x >> 6;           // wave == head; cols wave*64..
  int lane = threadIdx.x & 63;
  int lr = lane & 15, kg = lane >> 4;
  int col0 = wave * 64;

  // stage A tile [row0..row0+64) x [k0..k0+64) into As[buf]; source pre-swizzled
  auto stage = [&](int buf, int k0) {
#pragma unroll
    for (int j = 0; j < 2; ++j) {
      int Lb = j * 4096 + wave * 1024;          // wave-uniform LDS byte base
      int L = Lb + lane * 16;                   // this lane's linear slot
      int r = L >> 7;                           // row in tile (128B per row)
      int kb = (L & 127) ^ ((r & 7) << 4);      // pre-swizzled source column byte
      int rg = row0 + r; rg = rg < M ? rg : M - 1;
      const char* gsrc = (const char*)A + ((size_t)rg * K + k0) * 2 + kb;
      char* ldst = (char*)(&As[buf][0]) + Lb;
      __builtin_amdgcn_global_load_lds(
          (const __attribute__((address_space(1))) unsigned int*)gsrc,
          (__attribute__((address_space(3))) unsigned int*)ldst, 16, 0, 0);
    }
  };

  f32x4 acc[4][4];
#pragma unroll
  for (int i = 0; i < 4; ++i)
#pragma unroll
    for (int j = 0; j < 4; ++j) acc[i][j] = (f32x4){0.f, 0.f, 0.f, 0.f};
  f32x4 acc_er[4];
#pragma unroll
  for (int i = 0; i < 4; ++i) acc_er[i] = (f32x4){0.f, 0.f, 0.f, 0.f};

  int nt = K >> 6;   // BK = 64
  stage(0, 0);
  __syncthreads();
  for (int t = 0; t < nt; ++t) {
    if (t + 1 < nt) stage((t + 1) & 1, (t + 1) * 64);
    const char* abuf = (const char*)(&As[t & 1][0]);
#pragma unroll
    for (int s = 0; s < 2; ++s) {
      int kk = t * 64 + s * 32 + kg * 8;
      f16x8 af[4], bfr[4];
#pragma unroll
      for (int mt = 0; mt < 4; ++mt) {
        int r = mt * 16 + lr;
        int cb = ((s << 6) | (kg << 4)) ^ ((r & 7) << 4);   // swizzled read
        af[mt] = *reinterpret_cast<const f16x8*>(abuf + r * 128 + cb);
      }
#pragma unroll
      for (int ct = 0; ct < 4; ++ct) {
        int c = col0 + ct * 16 + lr;
        bfr[ct] = *reinterpret_cast<const f16x8*>(Wt + (size_t)c * K + kk);
      }
#pragma unroll
      for (int mt = 0; mt < 4; ++mt)
#pragma unroll
        for (int ct = 0; ct < 4; ++ct)
          acc[mt][ct] = __builtin_amdgcn_mfma_f32_16x16x32_f16(af[mt], bfr[ct], acc[mt][ct], 0, 0, 0);
      if (wave == 0) {
        f16x8 eb = *reinterpret_cast<const f16x8*>(wart + lr * 256 + kk);
#pragma unroll
        for (int mt = 0; mt < 4; ++mt)
          acc_er[mt] = __builtin_amdgcn_mfma_f32_16x16x32_f16(af[mt], eb, acc_er[mt], 0, 0, 0);
      }
    }
    __syncthreads();
  }

  // C-write: col = lane&15, row = (lane>>4)*4 + reg
#pragma unroll
  for (int mt = 0; mt < 4; ++mt) {
#pragma unroll
    for (int r = 0; r < 4; ++r) {
      int row = row0 + mt * 16 + kg * 4 + r;
      if (row < M) {
#pragma unroll
        for (int ct = 0; ct < 4; ++ct) {
          int col = col0 + ct * 16 + lr;
          Z[(size_t)row * HF + col] = (_Float16)acc[mt][ct][r];
        }
      }
    }
  }
  // fused el epilogue: this wave's 64 cols == head(=wave)'s 64 dims
  float al4[4];
#pragma unroll
  for (int ct = 0; ct < 4; ++ct) al4[ct] = al[col0 + ct * 16 + lr];
#pragma unroll
  for (int mt = 0; mt < 4; ++mt) {
#pragma unroll
    for (int r = 0; r < 4; ++r) {
      float p = acc[mt][0][r] * al4[0] + acc[mt][1][r] * al4[1] +
                acc[mt][2][r] * al4[2] + acc[mt][3][r] * al4[3];
#pragma unroll
      for (int off = 1; off < 16; off <<= 1) p += __shfl_xor(p, off);
      int row = row0 + mt * 16 + kg * 4 + r;
      if (lr == 0 && row < M) EL[(size_t)row * 4 + wave] = p;
    }
  }
  // er epilogue (wave 0 only): er[row][h=lr<4]
  if (wave == 0 && lr < 4) {
#pragma unroll
    for (int mt = 0; mt < 4; ++mt) {
#pragma unroll
      for (int r = 0; r < 4; ++r) {
        int row = row0 + mt * 16 + kg * 4 + r;
        if (row < M) ER[(size_t)row * 4 + lr] = acc_er[mt][r];
      }
    }
  }
}

// ---------- CSR build (both relations per dispatch) ----------
__global__ __launch_bounds__(256) void k_hist2(const int* __restrict__ d0, const int* __restrict__ d1,
                                               int* __restrict__ c0, int* __restrict__ c1) {
  int t = blockIdx.x * 256 + threadIdx.x;
  if (t < NE) atomicAdd(&c0[d0[t]], 1);
  else if (t < 2 * NE) atomicAdd(&c1[d1[t - NE]], 1);
}

__global__ __launch_bounds__(1024) void k_scan1_2(const int* __restrict__ c0, const int* __restrict__ c1,
                                                  int* __restrict__ rp0, int* __restrict__ rp1,
                                                  int* __restrict__ b0, int* __restrict__ b1, int nscan) {
  __shared__ int tmp[1024];
  int rel = blockIdx.x >= nscan;
  int blk = rel ? blockIdx.x - nscan : blockIdx.x;
  const int* counts = rel ? c1 : c0;
  int* rp = rel ? rp1 : rp0;
  int* bsum = rel ? b1 : b0;
  int i = blk * 1024 + threadIdx.x;
  int v = (i < NN) ? counts[i] : 0;
  tmp[threadIdx.x] = v;
  __syncthreads();
  for (int off = 1; off < 1024; off <<= 1) {
    int t = (threadIdx.x >= off) ? tmp[threadIdx.x - off] : 0;
    __syncthreads();
    tmp[threadIdx.x] += t;
    __syncthreads();
  }
  if (i < NN) rp[i] = tmp[threadIdx.x] - v;  // block-local exclusive
  if (threadIdx.x == 1023) bsum[blk] = tmp[1023];
}

__global__ __launch_bounds__(128) void k_scan2_2(int* __restrict__ b0, int* __restrict__ b1, int nb) {
  int rel = threadIdx.x >> 6;
  int l = threadIdx.x & 63;
  int* bsum = rel ? b1 : b0;
  int orig = (l < nb) ? bsum[l] : 0;
  int v = orig;
#pragma unroll
  for (int off = 1; off < 64; off <<= 1) {
    int t = __shfl_up(v, off);
    if (l >= off) v += t;
  }
  if (l < nb) bsum[l] = v - orig;  // exclusive
}

__global__ __launch_bounds__(1024) void k_scan3_2(int* __restrict__ rp0, int* __restrict__ rp1,
                                                  const int* __restrict__ b0, const int* __restrict__ b1,
                                                  int nscan) {
  int rel = blockIdx.x >= nscan;
  int blk = rel ? blockIdx.x - nscan : blockIdx.x;
  int* rp = rel ? rp1 : rp0;
  const int* bsum = rel ? b1 : b0;
  int i = blk * 1024 + threadIdx.x;
  if (i < NN) rp[i] += bsum[blk];
  if (i == 0) rp[NN] = NE;
}

__global__ __launch_bounds__(256) void k_scatter2(
    const int* __restrict__ s0, const int* __restrict__ d0,
    const int* __restrict__ s1, const int* __restrict__ d1,
    const int* __restrict__ rp0, const int* __restrict__ rp1,
    int* __restrict__ f0, int* __restrict__ f1,
    int* __restrict__ cs0, int* __restrict__ cs1) {
  int t = blockIdx.x * 256 + threadIdx.x;
  if (t < NE) {
    int d = d0[t];
    int pos = rp0[d] + atomicAdd(&f0[d], 1);
    cs0[pos] = s0[t];
  } else if (t < 2 * NE) {
    int e = t - NE;
    int d = d1[e];
    int pos = rp1[d] + atomicAdd(&f1[d], 1);
    cs1[pos] = s1[e];
  }
}

// ---------- degree-sort permutation (64 buckets, both relations) ----------
__global__ __launch_bounds__(256) void k_deghist2(const int* __restrict__ rp0,
                                                  const int* __restrict__ rp1,
                                                  int* __restrict__ dh) {  // dh[2][64]
  int t = blockIdx.x * 256 + threadIdx.x;
  if (t < NN) {
    int d = rp0[t + 1] - rp0[t];
    atomicAdd(&dh[min(d, 63)], 1);
  } else if (t < 2 * NN) {
    int n = t - NN;
    int d = rp1[n + 1] - rp1[n];
    atomicAdd(&dh[64 + min(d, 63)], 1);
  }
}

__global__ __launch_bounds__(128) void k_degscan(const int* __restrict__ dh, int* __restrict__ dofs) {
  int rel = threadIdx.x >> 6;
  int l = threadIdx.x & 63;
  int orig = dh[rel * 64 + l];
  int v = orig;
#pragma unroll
  for (int off = 1; off < 64; off <<= 1) {
    int t = __shfl_up(v, off);
    if (l >= off) v += t;
  }
  dofs[rel * 64 + l] = v - orig;  // exclusive
}

__global__ __launch_bounds__(256) void k_permscatter2(const int* __restrict__ rp0,
                                                      const int* __restrict__ rp1,
                                                      const int* __restrict__ dofs,
                                                      int* __restrict__ dfill,
                                                      int* __restrict__ perm0,
                                                      int* __restrict__ perm1) {
  int t = blockIdx.x * 256 + threadIdx.x;
  if (t < NN) {
    int b = min(rp0[t + 1] - rp0[t], 63);
    int pos = dofs[b] + atomicAdd(&dfill[b], 1);
    perm0[pos] = t;
  } else if (t < 2 * NN) {
    int n = t - NN;
    int b = min(rp1[n + 1] - rp1[n], 63);
    int pos = dofs[64 + b] + atomicAdd(&dfill[64 + b], 1);
    perm1[pos] = n;
  }
}

__device__ __forceinline__ float pick_h(float4 v, int h) {
  float r = v.x;
  r = (h == 1) ? v.y : r;
  r = (h == 2) ? v.z : r;
  r = (h == 3) ? v.w : r;
  return r;
}

// ---------- fused GAT aggregation, both relations per dispatch, degree-sorted ----------
template <typename OT>
__global__ __launch_bounds__(256) void k_agg2(
    const int* __restrict__ rpA, const int* __restrict__ csA, const int* __restrict__ permA,
    const float* __restrict__ elA, const float* __restrict__ erA,
    const _Float16* __restrict__ ZA, const float* __restrict__ bA, OT* __restrict__ oA,
    const int* __restrict__ rpB, const int* __restrict__ csB, const int* __restrict__ permB,
    const float* __restrict__ elB, const float* __restrict__ erB,
    const _Float16* __restrict__ ZB, const float* __restrict__ bB, OT* __restrict__ oB) {
  __shared__ float exs[4][256];
  __shared__ int ssrc[4][64];
  int nb = (NN + 3) / 4;
  int rel = blockIdx.x >= nb;
  int bid = rel ? blockIdx.x - nb : blockIdx.x;
  const int* rp = rel ? rpB : rpA;
  const int* csrc = rel ? csB : csA;
  const float* el = rel ? elB : elA;
  const float* er = rel ? erB : erA;
  const _Float16* Z = rel ? ZB : ZA;
  const float* bias = rel ? bB : bA;
  OT* out = rel ? oB : oA;

  int wv = threadIdx.x >> 6;
  int gid = bid * 4 + wv;
  if (gid >= NN) return;
  int wid = (rel ? permB : permA)[gid];
  int lane = threadIdx.x & 63;
  int half = lane >> 5, l5 = lane & 31;
  int c0 = l5 * 8;      // 8 cols per lane (halves cover full row)
  int h = l5 >> 3;      // head for cols c0..c0+7
  int beg = rp[wid], end = rp[wid + 1];
  int deg = end - beg;

  if (deg == 0) {
    if (half == 0) {
      float4 b0 = *reinterpret_cast<const float4*>(bias + c0);
      float4 b1 = *reinterpret_cast<const float4*>(bias + c0 + 4);
      if constexpr (std::is_same<OT, float>::value) {
        float4* op = reinterpret_cast<float4*>(out + (size_t)wid * HF + c0);
        op[0] = b0; op[1] = b1;
      } else {
        f16x8 o = {(_Float16)b0.x, (_Float16)b0.y, (_Float16)b0.z, (_Float16)b0.w,
                   (_Float16)b1.x, (_Float16)b1.y, (_Float16)b1.z, (_Float16)b1.w};
        *reinterpret_cast<f16x8*>(out + (size_t)wid * HF + c0) = o;
      }
    }
    return;
  }

  if (deg <= 64) {
    // ---- pass A: lane i owns edge i ----
    int s = 0;
    float4 x = {-1e30f, -1e30f, -1e30f, -1e30f};
    float4 b = *reinterpret_cast<const float4*>(er + (size_t)wid * 4);
    if (lane < deg) {
      s = csrc[beg + lane];
      float4 a = reinterpret_cast<const float4*>(el)[s];
      x.x = a.x + b.x; x.x = x.x >= 0.f ? x.x : 0.2f * x.x;
      x.y = a.y + b.y; x.y = x.y >= 0.f ? x.y : 0.2f * x.y;
      x.z = a.z + b.z; x.z = x.z >= 0.f ? x.z : 0.2f * x.z;
      x.w = a.w + b.w; x.w = x.w >= 0.f ? x.w : 0.2f * x.w;
    }
    float4 m = x;
#pragma unroll
    for (int off = 32; off > 0; off >>= 1) {
      m.x = fmaxf(m.x, __shfl_xor(m.x, off));
      m.y = fmaxf(m.y, __shfl_xor(m.y, off));
      m.z = fmaxf(m.z, __shfl_xor(m.z, off));
      m.w = fmaxf(m.w, __shfl_xor(m.w, off));
    }
    float4 ex = {0.f, 0.f, 0.f, 0.f};
    if (lane < deg) {
      ex.x = __expf(x.x - m.x);
      ex.y = __expf(x.y - m.y);
      ex.z = __expf(x.z - m.z);
      ex.w = __expf(x.w - m.w);
    }
    float4 sm = ex;
#pragma unroll
    for (int off = 32; off > 0; off >>= 1) {
      sm.x += __shfl_xor(sm.x, off);
      sm.y += __shfl_xor(sm.y, off);
      sm.z += __shfl_xor(sm.z, off);
      sm.w += __shfl_xor(sm.w, off);
    }
    float inv = 1.0f / pick_h(sm, h);
    if (lane < deg) {
      *reinterpret_cast<float4*>(&exs[wv][lane * 4]) = ex;
      ssrc[wv][lane] = s;
    }
    // ---- pass B: halves own alternate edges, 4-group unroll -> 8 gathers in flight ----
    float a8[8] = {0.f, 0.f, 0.f, 0.f, 0.f, 0.f, 0.f, 0.f};
    int j = half;
#define AGG_STEP(J)                                                        \
    {                                                                      \
      int sj = ssrc[wv][(J)];                                              \
      float wj = exs[wv][(J) * 4 + h];                                     \
      f16x8 z = *reinterpret_cast<const f16x8*>(Z + (size_t)sj * HF + c0); \
      _Pragma("unroll")                                                    \
      for (int q = 0; q < 8; ++q) a8[q] += wj * (float)z[q];               \
    }
    for (; j + 6 < deg; j += 8) {
      AGG_STEP(j); AGG_STEP(j + 2); AGG_STEP(j + 4); AGG_STEP(j + 6);
    }
    for (; j < deg; j += 2) { AGG_STEP(j); }
#undef AGG_STEP
#pragma unroll
    for (int q = 0; q < 8; ++q) a8[q] += __shfl_xor(a8[q], 32);
    if (half == 0) {
      float4 b0 = *reinterpret_cast<const float4*>(bias + c0);
      float4 b1 = *reinterpret_cast<const float4*>(bias + c0 + 4);
      float r0 = a8[0] * inv + b0.x, r1 = a8[1] * inv + b0.y;
      float r2 = a8[2] * inv + b0.z, r3 = a8[3] * inv + b0.w;
      float r4 = a8[4] * inv + b1.x, r5 = a8[5] * inv + b1.y;
      float r6 = a8[6] * inv + b1.z, r7 = a8[7] * inv + b1.w;
      if constexpr (std::is_same<OT, float>::value) {
        float4* op = reinterpret_cast<float4*>(out + (size_t)wid * HF + c0);
        op[0] = (float4){r0, r1, r2, r3};
        op[1] = (float4){r4, r5, r6, r7};
      } else {
        f16x8 o = {(_Float16)r0, (_Float16)r1, (_Float16)r2, (_Float16)r3,
                   (_Float16)r4, (_Float16)r5, (_Float16)r6, (_Float16)r7};
        *reinterpret_cast<f16x8*>(out + (size_t)wid * HF + c0) = o;
      }
    }
    return;
  }

  // ---- rare fallback (deg > 64): uniform two-pass, full-wave f16x4 mapping ----
  {
    int c4 = lane * 4;
    int h4 = lane >> 4;
    float4 b = *reinterpret_cast<const float4*>(er + (size_t)wid * 4);
    float4 m = {-1e30f, -1e30f, -1e30f, -1e30f};
    for (int e = beg; e < end; ++e) {
      int s = csrc[e];
      float4 a = reinterpret_cast<const float4*>(el)[s];
      float4 x;
      x.x = a.x + b.x; x.x = x.x >= 0.f ? x.x : 0.2f * x.x;
      x.y = a.y + b.y; x.y = x.y >= 0.f ? x.y : 0.2f * x.y;
      x.z = a.z + b.z; x.z = x.z >= 0.f ? x.z : 0.2f * x.z;
      x.w = a.w + b.w; x.w = x.w >= 0.f ? x.w : 0.2f * x.w;
      m.x = fmaxf(m.x, x.x); m.y = fmaxf(m.y, x.y);
      m.z = fmaxf(m.z, x.z); m.w = fmaxf(m.w, x.w);
    }
    float4 sm = {0.f, 0.f, 0.f, 0.f};
    float4 acc = {0.f, 0.f, 0.f, 0.f};
    for (int e = beg; e < end; ++e) {
      int s = csrc[e];
      float4 a = reinterpret_cast<const float4*>(el)[s];
      float4 x;
      x.x = a.x + b.x; x.x = x.x >= 0.f ? x.x : 0.2f * x.x;
      x.y = a.y + b.y; x.y = x.y >= 0.f ? x.y : 0.2f * x.y;
      x.z = a.z + b.z; x.z = x.z >= 0.f ? x.z : 0.2f * x.z;
      x.w = a.w + b.w; x.w = x.w >= 0.f ? x.w : 0.2f * x.w;
      float4 exv;
      exv.x = __expf(x.x - m.x); exv.y = __expf(x.y - m.y);
      exv.z = __expf(x.z - m.z); exv.w = __expf(x.w - m.w);
      sm.x += exv.x; sm.y += exv.y; sm.z += exv.z; sm.w += exv.w;
      float w0 = pick_h(exv, h4);
      f16x4 z0 = *reinterpret_cast<const f16x4*>(Z + (size_t)s * HF + c4);
      acc.x += w0 * (float)z0.x;
      acc.y += w0 * (float)z0.y;
      acc.z += w0 * (float)z0.z;
      acc.w += w0 * (float)z0.w;
    }
    float inv = 1.0f / pick_h(sm, h4);
    float4 bv = *reinterpret_cast<const float4*>(bias + c4);
    float r0 = acc.x * inv + bv.x, r1 = acc.y * inv + bv.y;
    float r2 = acc.z * inv + bv.z, r3 = acc.w * inv + bv.w;
    if constexpr (std::is_same<OT, float>::value) {
      *reinterpret_cast<float4*>(out + (size_t)wid * HF + c4) = (float4){r0, r1, r2, r3};
    } else {
      f16x4 o = {(_Float16)r0, (_Float16)r1, (_Float16)r2, (_Float16)r3};
      *reinterpret_cast<f16x4*>(out + (size_t)wid * HF + c4) = o;
    }
  }
}

// ---------- batchnorm stats, both sides per dispatch ----------
__global__ __launch_bounds__(256) void k_bn_stats2(const _Float16* __restrict__ XU,
                                                   const _Float16* __restrict__ XI,
                                                   float* __restrict__ su, float* __restrict__ qu,
                                                   float* __restrict__ si, float* __restrict__ qi) {
  int rel = blockIdx.x >> 9;  // grid = 1024
  int blk = blockIdx.x & 511;
  const _Float16* X = rel ? XI : XU;
  float* sums = rel ? si : su;
  float* sqs = rel ? qi : qu;
  int c = threadIdx.x;
  float s = 0.f, q = 0.f;
  for (int r = blk; r < NN; r += 512) {
    float v = (float)X[(size_t)r * HF + c];
    s += v;
    q += v * v;
  }
  atomicAdd(&sums[c], s);
  atomicAdd(&sqs[c], q);
}

// ---------- batchnorm apply, both sides per dispatch (RAW16 -> H16) ----------
__global__ __launch_bounds__(256) void k_bn_apply2(
    const _Float16* __restrict__ XU, const _Float16* __restrict__ XI,
    const float* __restrict__ su, const float* __restrict__ qu,
    const float* __restrict__ si, const float* __restrict__ qi,
    const float* __restrict__ gU, const float* __restrict__ btU,
    const float* __restrict__ gI, const float* __restrict__ btI,
    _Float16* __restrict__ YU, _Float16* __restrict__ YI, int act) {
  const int nb = NN * HF / 8 / 256;  // 6250
  int rel = blockIdx.x >= nb;
  int bid = rel ? blockIdx.x - nb : blockIdx.x;
  const _Float16* X = rel ? XI : XU;
  const float* sums = rel ? si : su;
  const float* sqs = rel ? qi : qu;
  const float* g = rel ? gI : gU;
  const float* bt = rel ? btI : btU;
  _Float16* Y = rel ? YI : YU;
  int gid = bid * 256 + threadIdx.x;
  int i0 = gid * 8;
  int c0 = i0 & 255;
  const float invN = 1.0f / NN;
  f16x8 xv = *reinterpret_cast<const f16x8*>(X + i0);
  float4 s0 = *reinterpret_cast<const float4*>(sums + c0);
  float4 s1 = *reinterpret_cast<const float4*>(sums + c0 + 4);
  float4 q0 = *reinterpret_cast<const float4*>(sqs + c0);
  float4 q1 = *reinterpret_cast<const float4*>(sqs + c0 + 4);
  float4 g0 = *reinterpret_cast<const float4*>(g + c0);
  float4 g1 = *reinterpret_cast<const float4*>(g + c0 + 4);
  float4 b0 = *reinterpret_cast<const float4*>(bt + c0);
  float4 b1 = *reinterpret_cast<const float4*>(bt + c0 + 4);
  float sa[8] = {s0.x, s0.y, s0.z, s0.w, s1.x, s1.y, s1.z, s1.w};
  float qa[8] = {q0.x, q0.y, q0.z, q0.w, q1.x, q1.y, q1.z, q1.w};
  float ga[8] = {g0.x, g0.y, g0.z, g0.w, g1.x, g1.y, g1.z, g1.w};
  float ba[8] = {b0.x, b0.y, b0.z, b0.w, b1.x, b1.y, b1.z, b1.w};
  f16x8 o;
#pragma unroll
  for (int j = 0; j < 8; ++j) {
    float mu = sa[j] * invN;
    float var = qa[j] * invN - mu * mu;
    float sc = rsqrtf(var + 1e-5f) * ga[j];
    float v = ((float)xv[j] - mu) * sc + ba[j];
    v = act ? tanhf(v) : (v >= 0.f ? v : 0.01f * v);
    o[j] = (_Float16)v;
  }
  *reinterpret_cast<f16x8*>(Y + i0) = o;
}

extern "C" void kernel_launch(void* const* d_in, const int* in_sizes, int n_in,
                              void* d_out, int out_size, void* d_ws, size_t ws_size,
                              hipStream_t stream) {
  (void)in_sizes; (void)n_in; (void)out_size; (void)ws_size;
  const float* x_user = (const float*)d_in[0];
  const float* x_item = (const float*)d_in[1];
  const int* ui_src = (const int*)d_in[2];
  const int* ui_dst = (const int*)d_in[3];
  const int* iu_src = (const int*)d_in[4];
  const int* iu_dst = (const int*)d_in[5];
  const float *Wp[4], *alp[4], *arp[4], *bp[4];
  for (int l = 0; l < 4; ++l) {
    Wp[l]  = (const float*)d_in[6 + 4 * l];
    alp[l] = (const float*)d_in[7 + 4 * l];
    arp[l] = (const float*)d_in[8 + 4 * l];
    bp[l]  = (const float*)d_in[9 + 4 * l];
  }
  const float* bng = (const float*)d_in[22];
  const float* bnb = (const float*)d_in[23];

  char* w = (char*)d_ws;
  auto alloc = [&](size_t bytes) -> void* {
    void* p = (void*)w;
    w += (bytes + 255) & ~(size_t)255;
    return p;
  };
  _Float16* XU16 = (_Float16*)alloc((size_t)NN * 128 * 2);
  _Float16* XI16 = (_Float16*)alloc((size_t)NN * 128 * 2);
  _Float16* H16U = (_Float16*)alloc((size_t)NN * HF * 2);
  _Float16* H16I = (_Float16*)alloc((size_t)NN * HF * 2);
  _Float16* Z0 = (_Float16*)alloc((size_t)NN * HF * 2);
  _Float16* Z1 = (_Float16*)alloc((size_t)NN * HF * 2);
  _Float16* RAW16U = (_Float16*)alloc((size_t)NN * HF * 2);
  _Float16* RAW16I = (_Float16*)alloc((size_t)NN * HF * 2);
  float* EL0 = (float*)alloc((size_t)NN * 4 * 4);
  float* ER0 = (float*)alloc((size_t)NN * 4 * 4);
  float* EL1 = (float*)alloc((size_t)NN * 4 * 4);
  float* ER1 = (float*)alloc((size_t)NN * 4 * 4);
  _Float16* WT = (_Float16*)alloc((size_t)8 * 65536 * 2);
  _Float16* WART = (_Float16*)alloc((size_t)8 * 4096 * 2);  // [8][16][256] fp16
  int* rp_ui = (int*)alloc((size_t)(NN + 1) * 4);
  int* rp_iu = (int*)alloc((size_t)(NN + 1) * 4);
  int* csrc_ui = (int*)alloc((size_t)NE * 4);
  int* csrc_iu = (int*)alloc((size_t)NE * 4);
  int* perm_ui = (int*)alloc((size_t)NN * 4);
  int* perm_iu = (int*)alloc((size_t)NN * 4);
  int* counts = (int*)alloc((size_t)4 * NN * 4);  // counts_ui | counts_iu | fill_ui | fill_iu
  int* bsum_ui = (int*)alloc((size_t)64 * 4);
  int* bsum_iu = (int*)alloc((size_t)64 * 4);
  int* degws = (int*)alloc((size_t)384 * 4);      // dh[128] | dofs[128] | dfill[128]
  float* stats = (float*)alloc((size_t)6 * 512 * 4);

  int* counts_ui = counts;
  int* counts_iu = counts + NN;
  int* fill_ui = counts + 2 * NN;
  int* fill_iu = counts + 3 * NN;
  int* dh = degws;
  int* dofs = degws + 128;
  int* dfill = degws + 256;

  hipMemsetAsync(counts, 0, (size_t)4 * NN * 4, stream);
  hipMemsetAsync(stats, 0, (size_t)6 * 512 * 4, stream);
  hipMemsetAsync(WART, 0, (size_t)8 * 4096 * 2, stream);
  hipMemsetAsync(degws, 0, (size_t)384 * 4, stream);

  // input conversion (one dispatch)
  int n4 = NN * 128 / 4;
  k_tofp16_2<<<(2 * n4 + 255) / 256, 256, 0, stream>>>(x_user, x_item, XU16, XI16, n4);

  // all weight transposes (one dispatch)
  TArgs ta;
  int cum = 0;
  for (int l = 0; l < 4; ++l) {
    int K = (l == 0) ? 128 : 256;
    for (int r = 0; r < 2; ++r) {
      int s = l * 2 + r;
      ta.W[s] = Wp[l] + (size_t)r * K * HF;
      ta.dst[s] = WT + (size_t)s * 65536;
      ta.K[s] = K;
      ta.cum[s] = cum;
      cum += K * 256;
    }
  }
  ta.cum[8] = cum;
  k_transpose_all<<<(cum + 255) / 256, 256, 0, stream>>>(ta);

  // all W.ar attn tables, fp16 padded (one dispatch)
  k_makeattn_all<<<(8 * 256 * 4 + 255) / 256, 256, 0, stream>>>(
      Wp[0], Wp[1], Wp[2], Wp[3], arp[0], arp[1], arp[2], arp[3], WART);

  // CSR build (both relations per dispatch)
  int egrid2 = (2 * NE + 255) / 256;
  int nscan = (NN + 1023) / 1024;
  k_hist2<<<egrid2, 256, 0, stream>>>(ui_dst, iu_dst, counts_ui, counts_iu);
  k_scan1_2<<<2 * nscan, 1024, 0, stream>>>(counts_ui, counts_iu, rp_ui, rp_iu, bsum_ui, bsum_iu, nscan);
  k_scan2_2<<<1, 128, 0, stream>>>(bsum_ui, bsum_iu, nscan);
  k_scan3_2<<<2 * nscan, 1024, 0, stream>>>(rp_ui, rp_iu, bsum_ui, bsum_iu, nscan);
  k_scatter2<<<egrid2, 256, 0, stream>>>(ui_src, ui_dst, iu_src, iu_dst, rp_ui, rp_iu,
                                         fill_ui, fill_iu, csrc_ui, csrc_iu);

  // degree-sorted permutations (both relations)
  int ngrid2 = (2 * NN + 255) / 256;
  k_deghist2<<<ngrid2, 256, 0, stream>>>(rp_ui, rp_iu, dh);
  k_degscan<<<1, 128, 0, stream>>>(dh, dofs);
  k_permscatter2<<<ngrid2, 256, 0, stream>>>(rp_ui, rp_iu, dofs, dfill, perm_ui, perm_iu);

  int agrid = (NN + 3) / 4;
  int nrow = (NN + 63) / 64;
  float* out_user = (float*)d_out;
  float* out_item = (float*)d_out + (size_t)NN * HF;

  for (int l = 0; l < 4; ++l) {
    int K = (l == 0) ? 128 : 256;
    const _Float16* Au = (l == 0) ? XU16 : H16U;
    const _Float16* Ai = (l == 0) ? XI16 : H16I;

    // GEMM pair: Z0 = hu@W0 (+el0, +er1), Z1 = hi@W1 (+el1, +er0)
    GArgs ga;
    ga.A0 = Au; ga.A1 = Ai;
    ga.Wt0 = WT + (size_t)(l * 2 + 0) * 65536;
    ga.Wt1 = WT + (size_t)(l * 2 + 1) * 65536;
    ga.Z0 = Z0; ga.Z1 = Z1;
    ga.al0 = alp[l] + 0; ga.al1 = alp[l] + 256;
    ga.EL0 = EL0; ga.EL1 = EL1;
    ga.wart_s0 = WART + (size_t)(l * 2 + 1) * 4096;  // side0 (A=hu) -> er1 = hu.(W1.ar1)
    ga.wart_s1 = WART + (size_t)(l * 2 + 0) * 4096;  // side1 (A=hi) -> er0 = hi.(W0.ar0)
    ga.ER_s0 = ER1; ga.ER_s1 = ER0;
    ga.M = NN; ga.K = K;
    k_gemm5<<<2 * nrow, 256, 0, stream>>>(ga);

    // aggregation pair: u->i (dst items, Z0) and i->u (dst users, Z1)
    if (l < 3)
      k_agg2<_Float16><<<2 * agrid, 256, 0, stream>>>(
          rp_ui, csrc_ui, perm_ui, EL0, ER0, Z0, bp[l] + 0, RAW16I,
          rp_iu, csrc_iu, perm_iu, EL1, ER1, Z1, bp[l] + 256, RAW16U);
    else
      k_agg2<float><<<2 * agrid, 256, 0, stream>>>(
          rp_ui, csrc_ui, perm_ui, EL0, ER0, Z0, bp[l] + 0, out_item,
          rp_iu, csrc_iu, perm_iu, EL1, ER1, Z1, bp[l] + 256, out_user);

    if (l < 3) {
      int act = (l == 2) ? 1 : 0;
      float* su = stats + (size_t)(l * 2 + 0) * 512;
      float* si = stats + (size_t)(l * 2 + 1) * 512;
      k_bn_stats2<<<1024, 256, 0, stream>>>(RAW16U, RAW16I, su, su + 256, si, si + 256);
      k_bn_apply2<<<2 * (NN * HF / 8 / 256), 256, 0, stream>>>(
          RAW16U, RAW16I, su, su + 256, si, si + 256,
          bng + (size_t)(l * 2 + 0) * 256, bnb + (size_t)(l * 2 + 0) * 256,
          bng + (size_t)(l * 2 + 1) * 256, bnb + (size_t)(l * 2 + 1) * 256,
          H16U, H16I, act);
    }
  }
}

// Round 13
// 992.246 us; speedup vs baseline: 1.3497x; 1.3497x over previous
//
#include <hip/hip_runtime.h>
#include <hip/hip_bf16.h>
#include <type_traits>

#define NN 50000     // nodes per side (users == items == 50000)
#define NE 600000    // edges per relation
#define HF 256       // hidden features

typedef float f32x4 __attribute__((ext_vector_type(4)));
typedef _Float16 f16x8 __attribute__((ext_vector_type(8)));
typedef _Float16 f16x4 __attribute__((ext_vector_type(4)));

// ---------- fp32 -> fp16 convert, both inputs in one dispatch ----------
__global__ __launch_bounds__(256) void k_tofp16_2(const float* __restrict__ A,
                                                  const float* __restrict__ B,
                                                  _Float16* __restrict__ OA,
                                                  _Float16* __restrict__ OB, int n4) {
  int i = blockIdx.x * 256 + threadIdx.x;
  const float* X = (i < n4) ? A : B;
  _Float16* Y = (i < n4) ? OA : OB;
  int j = (i < n4) ? i : i - n4;
  if (j < n4) {
    float4 v = reinterpret_cast<const float4*>(X)[j];
    f16x4 o = {(_Float16)v.x, (_Float16)v.y, (_Float16)v.z, (_Float16)v.w};
    reinterpret_cast<f16x4*>(Y)[j] = o;
  }
}

// ---------- all 8 W[K][256] -> Wt[256][K] transposes in one dispatch ----------
struct TArgs {
  const float* W[8];
  _Float16* dst[8];
  int K[8];
  int cum[9];
};
__global__ __launch_bounds__(256) void k_transpose_all(TArgs t) {
  int idx = blockIdx.x * 256 + threadIdx.x;
#pragma unroll
  for (int s = 0; s < 8; ++s) {
    if (idx >= t.cum[s] && idx < t.cum[s + 1]) {
      int local = idx - t.cum[s];
      int K = t.K[s];
      int k = local >> 8;
      int n = local & 255;
      t.dst[s][(size_t)n * K + k] = (_Float16)t.W[s][local];
    }
  }
}

// ---------- all W.ar attn tables, fp16 [16][256]-padded, in one dispatch ----------
__global__ __launch_bounds__(256) void k_makeattn_all(
    const float* __restrict__ W1, const float* __restrict__ W2,
    const float* __restrict__ W3, const float* __restrict__ W4,
    const float* __restrict__ ar1, const float* __restrict__ ar2,
    const float* __restrict__ ar3, const float* __restrict__ ar4,
    _Float16* __restrict__ wart) {   // [8][16][256] fp16, cols 4..15 stay zero
  int idx = blockIdx.x * 256 + threadIdx.x;
  if (idx >= 8 * 256 * 4) return;
  int h = idx & 3;
  int k = (idx >> 2) & 255;
  int s = idx >> 10;  // l*2+r
  int l = s >> 1, r = s & 1;
  int K = (l == 0) ? 128 : 256;
  if (k >= K) return;
  const float* W = (l == 0 ? W1 : l == 1 ? W2 : l == 2 ? W3 : W4) + (size_t)r * K * 256;
  const float* a = (l == 0 ? ar1 : l == 1 ? ar2 : l == 2 ? ar3 : ar4) + r * 256 + h * 64;
  const float* wrow = W + (size_t)k * 256 + h * 64;
  float sum = 0.f;
#pragma unroll 8
  for (int d = 0; d < 64; ++d) sum += wrow[d] * a[d];
  wart[(size_t)s * 4096 + h * 256 + k] = (_Float16)sum;
}

// ---------- GEMM v5b: 64x256 tile, LDS-staged A (swizzled) dbuf, fused el + er(MFMA) ----------
struct GArgs {
  const _Float16* A0; const _Float16* A1;     // post-BN activations
  const _Float16* Wt0; const _Float16* Wt1;
  _Float16* Z0; _Float16* Z1;
  const float* al0; const float* al1;
  float* EL0; float* EL1;
  const _Float16* wart_s0; const _Float16* wart_s1;  // [16][256] fp16 W.ar tables
  float* ER_s0; float* ER_s1;                 // side0 -> ER1, side1 -> ER0
  int M, K;
};

__global__ __launch_bounds__(256) void k_gemm5(GArgs ga) {
  __shared__ _Float16 As[2][64 * 64];    // 2 x 8 KB double buffer
  const int nrow = (NN + 63) / 64;       // 782
  int side = blockIdx.x >= nrow;
  int bid = side ? blockIdx.x - nrow : blockIdx.x;
  const _Float16* A = side ? ga.A1 : ga.A0;
  const _Float16* Wt = side ? ga.Wt1 : ga.Wt0;
  _Float16* Z = side ? ga.Z1 : ga.Z0;
  const float* al = side ? ga.al1 : ga.al0;
  float* EL = side ? ga.EL1 : ga.EL0;
  const _Float16* wart = side ? ga.wart_s1 : ga.wart_s0;
  float* ER = side ? ga.ER_s1 : ga.ER_s0;
  const int K = ga.K, M = ga.M;
  int row0 = bid * 64;
  int wave = threadIdx.x >> 6;           // wave == head; cols wave*64..
  int lane = threadIdx.x & 63;
  int lr = lane & 15, kg = lane >> 4;
  int col0 = wave * 64;

  // stage A tile [row0..row0+64) x [k0..k0+64) into As[buf]; source pre-swizzled
  auto stage = [&](int buf, int k0) {
#pragma unroll
    for (int j = 0; j < 2; ++j) {
      int Lb = j * 4096 + wave * 1024;          // wave-uniform LDS byte base
      int L = Lb + lane * 16;                   // this lane's linear slot
      int r = L >> 7;                           // row in tile (128B per row)
      int kb = (L & 127) ^ ((r & 7) << 4);      // pre-swizzled source column byte
      int rg = row0 + r; rg = rg < M ? rg : M - 1;
      const char* gsrc = (const char*)A + ((size_t)rg * K + k0) * 2 + kb;
      char* ldst = (char*)(&As[buf][0]) + Lb;
      __builtin_amdgcn_global_load_lds(
          (const __attribute__((address_space(1))) unsigned int*)gsrc,
          (__attribute__((address_space(3))) unsigned int*)ldst, 16, 0, 0);
    }
  };

  f32x4 acc[4][4];
#pragma unroll
  for (int i = 0; i < 4; ++i)
#pragma unroll
    for (int j = 0; j < 4; ++j) acc[i][j] = (f32x4){0.f, 0.f, 0.f, 0.f};
  f32x4 acc_er[4];
#pragma unroll
  for (int i = 0; i < 4; ++i) acc_er[i] = (f32x4){0.f, 0.f, 0.f, 0.f};

  int nt = K >> 6;   // BK = 64
  stage(0, 0);
  __syncthreads();
  for (int t = 0; t < nt; ++t) {
    if (t + 1 < nt) stage((t + 1) & 1, (t + 1) * 64);
    const char* abuf = (const char*)(&As[t & 1][0]);
#pragma unroll
    for (int s = 0; s < 2; ++s) {
      int kk = t * 64 + s * 32 + kg * 8;
      f16x8 af[4], bfr[4];
#pragma unroll
      for (int mt = 0; mt < 4; ++mt) {
        int r = mt * 16 + lr;
        int cb = ((s << 6) | (kg << 4)) ^ ((r & 7) << 4);   // swizzled read
        af[mt] = *reinterpret_cast<const f16x8*>(abuf + r * 128 + cb);
      }
#pragma unroll
      for (int ct = 0; ct < 4; ++ct) {
        int c = col0 + ct * 16 + lr;
        bfr[ct] = *reinterpret_cast<const f16x8*>(Wt + (size_t)c * K + kk);
      }
#pragma unroll
      for (int mt = 0; mt < 4; ++mt)
#pragma unroll
        for (int ct = 0; ct < 4; ++ct)
          acc[mt][ct] = __builtin_amdgcn_mfma_f32_16x16x32_f16(af[mt], bfr[ct], acc[mt][ct], 0, 0, 0);
      if (wave == 0) {
        f16x8 eb = *reinterpret_cast<const f16x8*>(wart + lr * 256 + kk);
#pragma unroll
        for (int mt = 0; mt < 4; ++mt)
          acc_er[mt] = __builtin_amdgcn_mfma_f32_16x16x32_f16(af[mt], eb, acc_er[mt], 0, 0, 0);
      }
    }
    __syncthreads();
  }

  // C-write: col = lane&15, row = (lane>>4)*4 + reg
#pragma unroll
  for (int mt = 0; mt < 4; ++mt) {
#pragma unroll
    for (int r = 0; r < 4; ++r) {
      int row = row0 + mt * 16 + kg * 4 + r;
      if (row < M) {
#pragma unroll
        for (int ct = 0; ct < 4; ++ct) {
          int col = col0 + ct * 16 + lr;
          Z[(size_t)row * HF + col] = (_Float16)acc[mt][ct][r];
        }
      }
    }
  }
  // fused el epilogue: this wave's 64 cols == head(=wave)'s 64 dims
  float al4[4];
#pragma unroll
  for (int ct = 0; ct < 4; ++ct) al4[ct] = al[col0 + ct * 16 + lr];
#pragma unroll
  for (int mt = 0; mt < 4; ++mt) {
#pragma unroll
    for (int r = 0; r < 4; ++r) {
      float p = acc[mt][0][r] * al4[0] + acc[mt][1][r] * al4[1] +
                acc[mt][2][r] * al4[2] + acc[mt][3][r] * al4[3];
#pragma unroll
      for (int off = 1; off < 16; off <<= 1) p += __shfl_xor(p, off);
      int row = row0 + mt * 16 + kg * 4 + r;
      if (lr == 0 && row < M) EL[(size_t)row * 4 + wave] = p;
    }
  }
  // er epilogue (wave 0 only): er[row][h=lr<4]
  if (wave == 0 && lr < 4) {
#pragma unroll
    for (int mt = 0; mt < 4; ++mt) {
#pragma unroll
      for (int r = 0; r < 4; ++r) {
        int row = row0 + mt * 16 + kg * 4 + r;
        if (row < M) ER[(size_t)row * 4 + lr] = acc_er[mt][r];
      }
    }
  }
}

// ---------- CSR build (both relations per dispatch) ----------
__global__ __launch_bounds__(256) void k_hist2(const int* __restrict__ d0, const int* __restrict__ d1,
                                               int* __restrict__ c0, int* __restrict__ c1) {
  int t = blockIdx.x * 256 + threadIdx.x;
  if (t < NE) atomicAdd(&c0[d0[t]], 1);
  else if (t < 2 * NE) atomicAdd(&c1[d1[t - NE]], 1);
}

__global__ __launch_bounds__(1024) void k_scan1_2(const int* __restrict__ c0, const int* __restrict__ c1,
                                                  int* __restrict__ rp0, int* __restrict__ rp1,
                                                  int* __restrict__ b0, int* __restrict__ b1, int nscan) {
  __shared__ int tmp[1024];
  int rel = blockIdx.x >= nscan;
  int blk = rel ? blockIdx.x - nscan : blockIdx.x;
  const int* counts = rel ? c1 : c0;
  int* rp = rel ? rp1 : rp0;
  int* bsum = rel ? b1 : b0;
  int i = blk * 1024 + threadIdx.x;
  int v = (i < NN) ? counts[i] : 0;
  tmp[threadIdx.x] = v;
  __syncthreads();
  for (int off = 1; off < 1024; off <<= 1) {
    int t = (threadIdx.x >= off) ? tmp[threadIdx.x - off] : 0;
    __syncthreads();
    tmp[threadIdx.x] += t;
    __syncthreads();
  }
  if (i < NN) rp[i] = tmp[threadIdx.x] - v;  // block-local exclusive
  if (threadIdx.x == 1023) bsum[blk] = tmp[1023];
}

__global__ __launch_bounds__(128) void k_scan2_2(int* __restrict__ b0, int* __restrict__ b1, int nb) {
  int rel = threadIdx.x >> 6;
  int l = threadIdx.x & 63;
  int* bsum = rel ? b1 : b0;
  int orig = (l < nb) ? bsum[l] : 0;
  int v = orig;
#pragma unroll
  for (int off = 1; off < 64; off <<= 1) {
    int t = __shfl_up(v, off);
    if (l >= off) v += t;
  }
  if (l < nb) bsum[l] = v - orig;  // exclusive
}

__global__ __launch_bounds__(1024) void k_scan3_2(int* __restrict__ rp0, int* __restrict__ rp1,
                                                  const int* __restrict__ b0, const int* __restrict__ b1,
                                                  int nscan) {
  int rel = blockIdx.x >= nscan;
  int blk = rel ? blockIdx.x - nscan : blockIdx.x;
  int* rp = rel ? rp1 : rp0;
  const int* bsum = rel ? b1 : b0;
  int i = blk * 1024 + threadIdx.x;
  if (i < NN) rp[i] += bsum[blk];
  if (i == 0) rp[NN] = NE;
}

__global__ __launch_bounds__(256) void k_scatter2(
    const int* __restrict__ s0, const int* __restrict__ d0,
    const int* __restrict__ s1, const int* __restrict__ d1,
    const int* __restrict__ rp0, const int* __restrict__ rp1,
    int* __restrict__ f0, int* __restrict__ f1,
    int* __restrict__ cs0, int* __restrict__ cs1) {
  int t = blockIdx.x * 256 + threadIdx.x;
  if (t < NE) {
    int d = d0[t];
    int pos = rp0[d] + atomicAdd(&f0[d], 1);
    cs0[pos] = s0[t];
  } else if (t < 2 * NE) {
    int e = t - NE;
    int d = d1[e];
    int pos = rp1[d] + atomicAdd(&f1[d], 1);
    cs1[pos] = s1[e];
  }
}

// ---------- degree-sort permutation (64 buckets, both relations, LDS-privatized) ----------
__global__ __launch_bounds__(256) void k_deghist2(const int* __restrict__ rp0,
                                                  const int* __restrict__ rp1,
                                                  int* __restrict__ dh) {  // dh[2][64]
  __shared__ int h[128];
  if (threadIdx.x < 128) h[threadIdx.x] = 0;
  __syncthreads();
  int t = blockIdx.x * 256 + threadIdx.x;
  if (t < NN) {
    atomicAdd(&h[min(rp0[t + 1] - rp0[t], 63)], 1);
  } else if (t < 2 * NN) {
    int n = t - NN;
    atomicAdd(&h[64 + min(rp1[n + 1] - rp1[n], 63)], 1);
  }
  __syncthreads();
  if (threadIdx.x < 128) {
    int v = h[threadIdx.x];
    if (v) atomicAdd(&dh[threadIdx.x], v);
  }
}

__global__ __launch_bounds__(128) void k_degscan(const int* __restrict__ dh, int* __restrict__ dofs) {
  int rel = threadIdx.x >> 6;
  int l = threadIdx.x & 63;
  int orig = dh[rel * 64 + l];
  int v = orig;
#pragma unroll
  for (int off = 1; off < 64; off <<= 1) {
    int t = __shfl_up(v, off);
    if (l >= off) v += t;
  }
  dofs[rel * 64 + l] = v - orig;  // exclusive
}

__global__ __launch_bounds__(256) void k_permscatter2(const int* __restrict__ rp0,
                                                      const int* __restrict__ rp1,
                                                      const int* __restrict__ dofs,
                                                      int* __restrict__ dfill,
                                                      int* __restrict__ perm0,
                                                      int* __restrict__ perm1) {
  __shared__ int lcnt[128];
  __shared__ int lbase[128];
  if (threadIdx.x < 128) lcnt[threadIdx.x] = 0;
  __syncthreads();
  int t = blockIdx.x * 256 + threadIdx.x;
  int bucket = -1, node = 0, rank = 0, rel = 0;
  if (t < NN) {
    node = t; rel = 0;
    bucket = min(rp0[t + 1] - rp0[t], 63);
    rank = atomicAdd(&lcnt[bucket], 1);
  } else if (t < 2 * NN) {
    node = t - NN; rel = 1;
    bucket = 64 + min(rp1[node + 1] - rp1[node], 63);
    rank = atomicAdd(&lcnt[bucket], 1);
  }
  __syncthreads();
  if (threadIdx.x < 128) {
    int v = lcnt[threadIdx.x];
    lbase[threadIdx.x] = v ? atomicAdd(&dfill[threadIdx.x], v) : 0;
  }
  __syncthreads();
  if (bucket >= 0) {
    int pos = dofs[bucket] + lbase[bucket] + rank;
    if (rel == 0) perm0[pos] = node;
    else perm1[pos] = node;
  }
}

__device__ __forceinline__ float pick_h(float4 v, int h) {
  float r = v.x;
  r = (h == 1) ? v.y : r;
  r = (h == 2) ? v.z : r;
  r = (h == 3) ? v.w : r;
  return r;
}

// ---------- fused GAT aggregation, both relations per dispatch, degree-sorted ----------
template <typename OT>
__global__ __launch_bounds__(256) void k_agg2(
    const int* __restrict__ rpA, const int* __restrict__ csA, const int* __restrict__ permA,
    const float* __restrict__ elA, const float* __restrict__ erA,
    const _Float16* __restrict__ ZA, const float* __restrict__ bA, OT* __restrict__ oA,
    const int* __restrict__ rpB, const int* __restrict__ csB, const int* __restrict__ permB,
    const float* __restrict__ elB, const float* __restrict__ erB,
    const _Float16* __restrict__ ZB, const float* __restrict__ bB, OT* __restrict__ oB) {
  __shared__ float exs[4][256];
  __shared__ int ssrc[4][64];
  int nb = (NN + 3) / 4;
  int rel = blockIdx.x >= nb;
  int bid = rel ? blockIdx.x - nb : blockIdx.x;
  const int* rp = rel ? rpB : rpA;
  const int* csrc = rel ? csB : csA;
  const float* el = rel ? elB : elA;
  const float* er = rel ? erB : erA;
  const _Float16* Z = rel ? ZB : ZA;
  const float* bias = rel ? bB : bA;
  OT* out = rel ? oB : oA;

  int wv = threadIdx.x >> 6;
  int gid = bid * 4 + wv;
  if (gid >= NN) return;
  int wid = (rel ? permB : permA)[gid];
  int lane = threadIdx.x & 63;
  int half = lane >> 5, l5 = lane & 31;
  int c0 = l5 * 8;      // 8 cols per lane (halves cover full row)
  int h = l5 >> 3;      // head for cols c0..c0+7
  int beg = rp[wid], end = rp[wid + 1];
  int deg = end - beg;

  if (deg == 0) {
    if (half == 0) {
      float4 b0 = *reinterpret_cast<const float4*>(bias + c0);
      float4 b1 = *reinterpret_cast<const float4*>(bias + c0 + 4);
      if constexpr (std::is_same<OT, float>::value) {
        float4* op = reinterpret_cast<float4*>(out + (size_t)wid * HF + c0);
        op[0] = b0; op[1] = b1;
      } else {
        f16x8 o = {(_Float16)b0.x, (_Float16)b0.y, (_Float16)b0.z, (_Float16)b0.w,
                   (_Float16)b1.x, (_Float16)b1.y, (_Float16)b1.z, (_Float16)b1.w};
        *reinterpret_cast<f16x8*>(out + (size_t)wid * HF + c0) = o;
      }
    }
    return;
  }

  if (deg <= 64) {
    // ---- pass A: lane i owns edge i ----
    int s = 0;
    float4 x = {-1e30f, -1e30f, -1e30f, -1e30f};
    float4 b = *reinterpret_cast<const float4*>(er + (size_t)wid * 4);
    if (lane < deg) {
      s = csrc[beg + lane];
      float4 a = reinterpret_cast<const float4*>(el)[s];
      x.x = a.x + b.x; x.x = x.x >= 0.f ? x.x : 0.2f * x.x;
      x.y = a.y + b.y; x.y = x.y >= 0.f ? x.y : 0.2f * x.y;
      x.z = a.z + b.z; x.z = x.z >= 0.f ? x.z : 0.2f * x.z;
      x.w = a.w + b.w; x.w = x.w >= 0.f ? x.w : 0.2f * x.w;
    }
    float4 m = x;
#pragma unroll
    for (int off = 32; off > 0; off >>= 1) {
      m.x = fmaxf(m.x, __shfl_xor(m.x, off));
      m.y = fmaxf(m.y, __shfl_xor(m.y, off));
      m.z = fmaxf(m.z, __shfl_xor(m.z, off));
      m.w = fmaxf(m.w, __shfl_xor(m.w, off));
    }
    float4 ex = {0.f, 0.f, 0.f, 0.f};
    if (lane < deg) {
      ex.x = __expf(x.x - m.x);
      ex.y = __expf(x.y - m.y);
      ex.z = __expf(x.z - m.z);
      ex.w = __expf(x.w - m.w);
    }
    float4 sm = ex;
#pragma unroll
    for (int off = 32; off > 0; off >>= 1) {
      sm.x += __shfl_xor(sm.x, off);
      sm.y += __shfl_xor(sm.y, off);
      sm.z += __shfl_xor(sm.z, off);
      sm.w += __shfl_xor(sm.w, off);
    }
    float inv = 1.0f / pick_h(sm, h);
    if (lane < deg) {
      *reinterpret_cast<float4*>(&exs[wv][lane * 4]) = ex;
      ssrc[wv][lane] = s;
    }
    // ---- pass B: halves own alternate edges, 4-group unroll -> 8 gathers in flight ----
    float a8[8] = {0.f, 0.f, 0.f, 0.f, 0.f, 0.f, 0.f, 0.f};
    int j = half;
#define AGG_STEP(J)                                                        \
    {                                                                      \
      int sj = ssrc[wv][(J)];                                              \
      float wj = exs[wv][(J) * 4 + h];                                     \
      f16x8 z = *reinterpret_cast<const f16x8*>(Z + (size_t)sj * HF + c0); \
      _Pragma("unroll")                                                    \
      for (int q = 0; q < 8; ++q) a8[q] += wj * (float)z[q];               \
    }
    for (; j + 6 < deg; j += 8) {
      AGG_STEP(j); AGG_STEP(j + 2); AGG_STEP(j + 4); AGG_STEP(j + 6);
    }
    for (; j < deg; j += 2) { AGG_STEP(j); }
#undef AGG_STEP
#pragma unroll
    for (int q = 0; q < 8; ++q) a8[q] += __shfl_xor(a8[q], 32);
    if (half == 0) {
      float4 b0 = *reinterpret_cast<const float4*>(bias + c0);
      float4 b1 = *reinterpret_cast<const float4*>(bias + c0 + 4);
      float r0 = a8[0] * inv + b0.x, r1 = a8[1] * inv + b0.y;
      float r2 = a8[2] * inv + b0.z, r3 = a8[3] * inv + b0.w;
      float r4 = a8[4] * inv + b1.x, r5 = a8[5] * inv + b1.y;
      float r6 = a8[6] * inv + b1.z, r7 = a8[7] * inv + b1.w;
      if constexpr (std::is_same<OT, float>::value) {
        float4* op = reinterpret_cast<float4*>(out + (size_t)wid * HF + c0);
        op[0] = (float4){r0, r1, r2, r3};
        op[1] = (float4){r4, r5, r6, r7};
      } else {
        f16x8 o = {(_Float16)r0, (_Float16)r1, (_Float16)r2, (_Float16)r3,
                   (_Float16)r4, (_Float16)r5, (_Float16)r6, (_Float16)r7};
        *reinterpret_cast<f16x8*>(out + (size_t)wid * HF + c0) = o;
      }
    }
    return;
  }

  // ---- rare fallback (deg > 64): uniform two-pass, full-wave f16x4 mapping ----
  {
    int c4 = lane * 4;
    int h4 = lane >> 4;
    float4 b = *reinterpret_cast<const float4*>(er + (size_t)wid * 4);
    float4 m = {-1e30f, -1e30f, -1e30f, -1e30f};
    for (int e = beg; e < end; ++e) {
      int s = csrc[e];
      float4 a = reinterpret_cast<const float4*>(el)[s];
      float4 x;
      x.x = a.x + b.x; x.x = x.x >= 0.f ? x.x : 0.2f * x.x;
      x.y = a.y + b.y; x.y = x.y >= 0.f ? x.y : 0.2f * x.y;
      x.z = a.z + b.z; x.z = x.z >= 0.f ? x.z : 0.2f * x.z;
      x.w = a.w + b.w; x.w = x.w >= 0.f ? x.w : 0.2f * x.w;
      m.x = fmaxf(m.x, x.x); m.y = fmaxf(m.y, x.y);
      m.z = fmaxf(m.z, x.z); m.w = fmaxf(m.w, x.w);
    }
    float4 sm = {0.f, 0.f, 0.f, 0.f};
    float4 acc = {0.f, 0.f, 0.f, 0.f};
    for (int e = beg; e < end; ++e) {
      int s = csrc[e];
      float4 a = reinterpret_cast<const float4*>(el)[s];
      float4 x;
      x.x = a.x + b.x; x.x = x.x >= 0.f ? x.x : 0.2f * x.x;
      x.y = a.y + b.y; x.y = x.y >= 0.f ? x.y : 0.2f * x.y;
      x.z = a.z + b.z; x.z = x.z >= 0.f ? x.z : 0.2f * x.z;
      x.w = a.w + b.w; x.w = x.w >= 0.f ? x.w : 0.2f * x.w;
      float4 exv;
      exv.x = __expf(x.x - m.x); exv.y = __expf(x.y - m.y);
      exv.z = __expf(x.z - m.z); exv.w = __expf(x.w - m.w);
      sm.x += exv.x; sm.y += exv.y; sm.z += exv.z; sm.w += exv.w;
      float w0 = pick_h(exv, h4);
      f16x4 z0 = *reinterpret_cast<const f16x4*>(Z + (size_t)s * HF + c4);
      acc.x += w0 * (float)z0.x;
      acc.y += w0 * (float)z0.y;
      acc.z += w0 * (float)z0.z;
      acc.w += w0 * (float)z0.w;
    }
    float inv = 1.0f / pick_h(sm, h4);
    float4 bv = *reinterpret_cast<const float4*>(bias + c4);
    float r0 = acc.x * inv + bv.x, r1 = acc.y * inv + bv.y;
    float r2 = acc.z * inv + bv.z, r3 = acc.w * inv + bv.w;
    if constexpr (std::is_same<OT, float>::value) {
      *reinterpret_cast<float4*>(out + (size_t)wid * HF + c4) = (float4){r0, r1, r2, r3};
    } else {
      f16x4 o = {(_Float16)r0, (_Float16)r1, (_Float16)r2, (_Float16)r3};
      *reinterpret_cast<f16x4*>(out + (size_t)wid * HF + c4) = o;
    }
  }
}

// ---------- batchnorm stats, both sides per dispatch ----------
__global__ __launch_bounds__(256) void k_bn_stats2(const _Float16* __restrict__ XU,
                                                   const _Float16* __restrict__ XI,
                                                   float* __restrict__ su, float* __restrict__ qu,
                                                   float* __restrict__ si, float* __restrict__ qi) {
  int rel = blockIdx.x >> 9;  // grid = 1024
  int blk = blockIdx.x & 511;
  const _Float16* X = rel ? XI : XU;
  float* sums = rel ? si : su;
  float* sqs = rel ? qi : qu;
  int c = threadIdx.x;
  float s = 0.f, q = 0.f;
  for (int r = blk; r < NN; r += 512) {
    float v = (float)X[(size_t)r * HF + c];
    s += v;
    q += v * v;
  }
  atomicAdd(&sums[c], s);
  atomicAdd(&sqs[c], q);
}

// ---------- batchnorm apply, both sides per dispatch (RAW16 -> H16) ----------
__global__ __launch_bounds__(256) void k_bn_apply2(
    const _Float16* __restrict__ XU, const _Float16* __restrict__ XI,
    const float* __restrict__ su, const float* __restrict__ qu,
    const float* __restrict__ si, const float* __restrict__ qi,
    const float* __restrict__ gU, const float* __restrict__ btU,
    const float* __restrict__ gI, const float* __restrict__ btI,
    _Float16* __restrict__ YU, _Float16* __restrict__ YI, int act) {
  const int nb = NN * HF / 8 / 256;  // 6250
  int rel = blockIdx.x >= nb;
  int bid = rel ? blockIdx.x - nb : blockIdx.x;
  const _Float16* X = rel ? XI : XU;
  const float* sums = rel ? si : su;
  const float* sqs = rel ? qi : qu;
  const float* g = rel ? gI : gU;
  const float* bt = rel ? btI : btU;
  _Float16* Y = rel ? YI : YU;
  int gid = bid * 256 + threadIdx.x;
  int i0 = gid * 8;
  int c0 = i0 & 255;
  const float invN = 1.0f / NN;
  f16x8 xv = *reinterpret_cast<const f16x8*>(X + i0);
  float4 s0 = *reinterpret_cast<const float4*>(sums + c0);
  float4 s1 = *reinterpret_cast<const float4*>(sums + c0 + 4);
  float4 q0 = *reinterpret_cast<const float4*>(sqs + c0);
  float4 q1 = *reinterpret_cast<const float4*>(sqs + c0 + 4);
  float4 g0 = *reinterpret_cast<const float4*>(g + c0);
  float4 g1 = *reinterpret_cast<const float4*>(g + c0 + 4);
  float4 b0 = *reinterpret_cast<const float4*>(bt + c0);
  float4 b1 = *reinterpret_cast<const float4*>(bt + c0 + 4);
  float sa[8] = {s0.x, s0.y, s0.z, s0.w, s1.x, s1.y, s1.z, s1.w};
  float qa[8] = {q0.x, q0.y, q0.z, q0.w, q1.x, q1.y, q1.z, q1.w};
  float ga[8] = {g0.x, g0.y, g0.z, g0.w, g1.x, g1.y, g1.z, g1.w};
  float ba[8] = {b0.x, b0.y, b0.z, b0.w, b1.x, b1.y, b1.z, b1.w};
  f16x8 o;
#pragma unroll
  for (int j = 0; j < 8; ++j) {
    float mu = sa[j] * invN;
    float var = qa[j] * invN - mu * mu;
    float sc = rsqrtf(var + 1e-5f) * ga[j];
    float v = ((float)xv[j] - mu) * sc + ba[j];
    v = act ? tanhf(v) : (v >= 0.f ? v : 0.01f * v);
    o[j] = (_Float16)v;
  }
  *reinterpret_cast<f16x8*>(Y + i0) = o;
}

extern "C" void kernel_launch(void* const* d_in, const int* in_sizes, int n_in,
                              void* d_out, int out_size, void* d_ws, size_t ws_size,
                              hipStream_t stream) {
  (void)in_sizes; (void)n_in; (void)out_size; (void)ws_size;
  const float* x_user = (const float*)d_in[0];
  const float* x_item = (const float*)d_in[1];
  const int* ui_src = (const int*)d_in[2];
  const int* ui_dst = (const int*)d_in[3];
  const int* iu_src = (const int*)d_in[4];
  const int* iu_dst = (const int*)d_in[5];
  const float *Wp[4], *alp[4], *arp[4], *bp[4];
  for (int l = 0; l < 4; ++l) {
    Wp[l]  = (const float*)d_in[6 + 4 * l];
    alp[l] = (const float*)d_in[7 + 4 * l];
    arp[l] = (const float*)d_in[8 + 4 * l];
    bp[l]  = (const float*)d_in[9 + 4 * l];
  }
  const float* bng = (const float*)d_in[22];
  const float* bnb = (const float*)d_in[23];

  char* w = (char*)d_ws;
  auto alloc = [&](size_t bytes) -> void* {
    void* p = (void*)w;
    w += (bytes + 255) & ~(size_t)255;
    return p;
  };
  _Float16* XU16 = (_Float16*)alloc((size_t)NN * 128 * 2);
  _Float16* XI16 = (_Float16*)alloc((size_t)NN * 128 * 2);
  _Float16* H16U = (_Float16*)alloc((size_t)NN * HF * 2);
  _Float16* H16I = (_Float16*)alloc((size_t)NN * HF * 2);
  _Float16* Z0 = (_Float16*)alloc((size_t)NN * HF * 2);
  _Float16* Z1 = (_Float16*)alloc((size_t)NN * HF * 2);
  _Float16* RAW16U = (_Float16*)alloc((size_t)NN * HF * 2);
  _Float16* RAW16I = (_Float16*)alloc((size_t)NN * HF * 2);
  float* EL0 = (float*)alloc((size_t)NN * 4 * 4);
  float* ER0 = (float*)alloc((size_t)NN * 4 * 4);
  float* EL1 = (float*)alloc((size_t)NN * 4 * 4);
  float* ER1 = (float*)alloc((size_t)NN * 4 * 4);
  _Float16* WT = (_Float16*)alloc((size_t)8 * 65536 * 2);
  _Float16* WART = (_Float16*)alloc((size_t)8 * 4096 * 2);  // [8][16][256] fp16
  int* rp_ui = (int*)alloc((size_t)(NN + 1) * 4);
  int* rp_iu = (int*)alloc((size_t)(NN + 1) * 4);
  int* csrc_ui = (int*)alloc((size_t)NE * 4);
  int* csrc_iu = (int*)alloc((size_t)NE * 4);
  int* perm_ui = (int*)alloc((size_t)NN * 4);
  int* perm_iu = (int*)alloc((size_t)NN * 4);
  int* counts = (int*)alloc((size_t)4 * NN * 4);  // counts_ui | counts_iu | fill_ui | fill_iu
  int* bsum_ui = (int*)alloc((size_t)64 * 4);
  int* bsum_iu = (int*)alloc((size_t)64 * 4);
  int* degws = (int*)alloc((size_t)384 * 4);      // dh[128] | dofs[128] | dfill[128]
  float* stats = (float*)alloc((size_t)6 * 512 * 4);

  int* counts_ui = counts;
  int* counts_iu = counts + NN;
  int* fill_ui = counts + 2 * NN;
  int* fill_iu = counts + 3 * NN;
  int* dh = degws;
  int* dofs = degws + 128;
  int* dfill = degws + 256;

  hipMemsetAsync(counts, 0, (size_t)4 * NN * 4, stream);
  hipMemsetAsync(stats, 0, (size_t)6 * 512 * 4, stream);
  hipMemsetAsync(WART, 0, (size_t)8 * 4096 * 2, stream);
  hipMemsetAsync(degws, 0, (size_t)384 * 4, stream);

  // input conversion (one dispatch)
  int n4 = NN * 128 / 4;
  k_tofp16_2<<<(2 * n4 + 255) / 256, 256, 0, stream>>>(x_user, x_item, XU16, XI16, n4);

  // all weight transposes (one dispatch)
  TArgs ta;
  int cum = 0;
  for (int l = 0; l < 4; ++l) {
    int K = (l == 0) ? 128 : 256;
    for (int r = 0; r < 2; ++r) {
      int s = l * 2 + r;
      ta.W[s] = Wp[l] + (size_t)r * K * HF;
      ta.dst[s] = WT + (size_t)s * 65536;
      ta.K[s] = K;
      ta.cum[s] = cum;
      cum += K * 256;
    }
  }
  ta.cum[8] = cum;
  k_transpose_all<<<(cum + 255) / 256, 256, 0, stream>>>(ta);

  // all W.ar attn tables, fp16 padded (one dispatch)
  k_makeattn_all<<<(8 * 256 * 4 + 255) / 256, 256, 0, stream>>>(
      Wp[0], Wp[1], Wp[2], Wp[3], arp[0], arp[1], arp[2], arp[3], WART);

  // CSR build (both relations per dispatch)
  int egrid2 = (2 * NE + 255) / 256;
  int nscan = (NN + 1023) / 1024;
  k_hist2<<<egrid2, 256, 0, stream>>>(ui_dst, iu_dst, counts_ui, counts_iu);
  k_scan1_2<<<2 * nscan, 1024, 0, stream>>>(counts_ui, counts_iu, rp_ui, rp_iu, bsum_ui, bsum_iu, nscan);
  k_scan2_2<<<1, 128, 0, stream>>>(bsum_ui, bsum_iu, nscan);
  k_scan3_2<<<2 * nscan, 1024, 0, stream>>>(rp_ui, rp_iu, bsum_ui, bsum_iu, nscan);
  k_scatter2<<<egrid2, 256, 0, stream>>>(ui_src, ui_dst, iu_src, iu_dst, rp_ui, rp_iu,
                                         fill_ui, fill_iu, csrc_ui, csrc_iu);

  // degree-sorted permutations (both relations, LDS-privatized atomics)
  int ngrid2 = (2 * NN + 255) / 256;
  k_deghist2<<<ngrid2, 256, 0, stream>>>(rp_ui, rp_iu, dh);
  k_degscan<<<1, 128, 0, stream>>>(dh, dofs);
  k_permscatter2<<<ngrid2, 256, 0, stream>>>(rp_ui, rp_iu, dofs, dfill, perm_ui, perm_iu);

  int agrid = (NN + 3) / 4;
  int nrow = (NN + 63) / 64;
  float* out_user = (float*)d_out;
  float* out_item = (float*)d_out + (size_t)NN * HF;

  for (int l = 0; l < 4; ++l) {
    int K = (l == 0) ? 128 : 256;
    const _Float16* Au = (l == 0) ? XU16 : H16U;
    const _Float16* Ai = (l == 0) ? XI16 : H16I;

    // GEMM pair: Z0 = hu@W0 (+el0, +er1), Z1 = hi@W1 (+el1, +er0)
    GArgs ga;
    ga.A0 = Au; ga.A1 = Ai;
    ga.Wt0 = WT + (size_t)(l * 2 + 0) * 65536;
    ga.Wt1 = WT + (size_t)(l * 2 + 1) * 65536;
    ga.Z0 = Z0; ga.Z1 = Z1;
    ga.al0 = alp[l] + 0; ga.al1 = alp[l] + 256;
    ga.EL0 = EL0; ga.EL1 = EL1;
    ga.wart_s0 = WART + (size_t)(l * 2 + 1) * 4096;  // side0 (A=hu) -> er1 = hu.(W1.ar1)
    ga.wart_s1 = WART + (size_t)(l * 2 + 0) * 4096;  // side1 (A=hi) -> er0 = hi.(W0.ar0)
    ga.ER_s0 = ER1; ga.ER_s1 = ER0;
    ga.M = NN; ga.K = K;
    k_gemm5<<<2 * nrow, 256, 0, stream>>>(ga);

    // aggregation pair: u->i (dst items, Z0) and i->u (dst users, Z1)
    if (l < 3)
      k_agg2<_Float16><<<2 * agrid, 256, 0, stream>>>(
          rp_ui, csrc_ui, perm_ui, EL0, ER0, Z0, bp[l] + 0, RAW16I,
          rp_iu, csrc_iu, perm_iu, EL1, ER1, Z1, bp[l] + 256, RAW16U);
    else
      k_agg2<float><<<2 * agrid, 256, 0, stream>>>(
          rp_ui, csrc_ui, perm_ui, EL0, ER0, Z0, bp[l] + 0, out_item,
          rp_iu, csrc_iu, perm_iu, EL1, ER1, Z1, bp[l] + 256, out_user);

    if (l < 3) {
      int act = (l == 2) ? 1 : 0;
      float* su = stats + (size_t)(l * 2 + 0) * 512;
      float* si = stats + (size_t)(l * 2 + 1) * 512;
      k_bn_stats2<<<1024, 256, 0, stream>>>(RAW16U, RAW16I, su, su + 256, si, si + 256);
      k_bn_apply2<<<2 * (NN * HF / 8 / 256), 256, 0, stream>>>(
          RAW16U, RAW16I, su, su + 256, si, si + 256,
          bng + (size_t)(l * 2 + 0) * 256, bnb + (size_t)(l * 2 + 0) * 256,
          bng + (size_t)(l * 2 + 1) * 256, bnb + (size_t)(l * 2 + 1) * 256,
          H16U, H16I, act);
    }
  }
}

// Round 14
// 974.863 us; speedup vs baseline: 1.3738x; 1.0178x over previous
//
#include <hip/hip_runtime.h>
#include <hip/hip_bf16.h>
#include <type_traits>

#define NN 50000     // nodes per side (users == items == 50000)
#define NE 600000    // edges per relation
#define HF 256       // hidden features

typedef float f32x4 __attribute__((ext_vector_type(4)));
typedef _Float16 f16x8 __attribute__((ext_vector_type(8)));
typedef _Float16 f16x4 __attribute__((ext_vector_type(4)));
typedef _Float16 f16x2 __attribute__((ext_vector_type(2)));

// ---------- fp32 -> fp16 convert, both inputs in one dispatch ----------
__global__ __launch_bounds__(256) void k_tofp16_2(const float* __restrict__ A,
                                                  const float* __restrict__ B,
                                                  _Float16* __restrict__ OA,
                                                  _Float16* __restrict__ OB, int n4) {
  int i = blockIdx.x * 256 + threadIdx.x;
  const float* X = (i < n4) ? A : B;
  _Float16* Y = (i < n4) ? OA : OB;
  int j = (i < n4) ? i : i - n4;
  if (j < n4) {
    float4 v = reinterpret_cast<const float4*>(X)[j];
    f16x4 o = {(_Float16)v.x, (_Float16)v.y, (_Float16)v.z, (_Float16)v.w};
    reinterpret_cast<f16x4*>(Y)[j] = o;
  }
}

// ---------- all 8 W[K][256] -> Wt[256][K] transposes in one dispatch ----------
struct TArgs {
  const float* W[8];
  _Float16* dst[8];
  int K[8];
  int cum[9];
};
__global__ __launch_bounds__(256) void k_transpose_all(TArgs t) {
  int idx = blockIdx.x * 256 + threadIdx.x;
#pragma unroll
  for (int s = 0; s < 8; ++s) {
    if (idx >= t.cum[s] && idx < t.cum[s + 1]) {
      int local = idx - t.cum[s];
      int K = t.K[s];
      int k = local >> 8;
      int n = local & 255;
      t.dst[s][(size_t)n * K + k] = (_Float16)t.W[s][local];
    }
  }
}

// ---------- all W.ar attn tables, fp16 [16][256]-padded, in one dispatch ----------
__global__ __launch_bounds__(256) void k_makeattn_all(
    const float* __restrict__ W1, const float* __restrict__ W2,
    const float* __restrict__ W3, const float* __restrict__ W4,
    const float* __restrict__ ar1, const float* __restrict__ ar2,
    const float* __restrict__ ar3, const float* __restrict__ ar4,
    _Float16* __restrict__ wart) {   // [8][16][256] fp16, cols 4..15 stay zero
  int idx = blockIdx.x * 256 + threadIdx.x;
  if (idx >= 8 * 256 * 4) return;
  int h = idx & 3;
  int k = (idx >> 2) & 255;
  int s = idx >> 10;  // l*2+r
  int l = s >> 1, r = s & 1;
  int K = (l == 0) ? 128 : 256;
  if (k >= K) return;
  const float* W = (l == 0 ? W1 : l == 1 ? W2 : l == 2 ? W3 : W4) + (size_t)r * K * 256;
  const float* a = (l == 0 ? ar1 : l == 1 ? ar2 : l == 2 ? ar3 : ar4) + r * 256 + h * 64;
  const float* wrow = W + (size_t)k * 256 + h * 64;
  float sum = 0.f;
#pragma unroll 8
  for (int d = 0; d < 64; ++d) sum += wrow[d] * a[d];
  wart[(size_t)s * 4096 + h * 256 + k] = (_Float16)sum;
}

// ---------- GEMM v5b: 64x256 tile, LDS-staged A (swizzled) dbuf, fused el + er(MFMA) ----------
struct GArgs {
  const _Float16* A0; const _Float16* A1;     // post-BN activations
  const _Float16* Wt0; const _Float16* Wt1;
  _Float16* Z0; _Float16* Z1;
  const float* al0; const float* al1;
  float* EL0; float* EL1;
  const _Float16* wart_s0; const _Float16* wart_s1;  // [16][256] fp16 W.ar tables
  float* ER_s0; float* ER_s1;                 // side0 -> ER1, side1 -> ER0
  int M, K;
};

__global__ __launch_bounds__(256) void k_gemm5(GArgs ga) {
  __shared__ _Float16 As[2][64 * 64];    // 2 x 8 KB double buffer
  const int nrow = (NN + 63) / 64;       // 782
  int side = blockIdx.x >= nrow;
  int bid = side ? blockIdx.x - nrow : blockIdx.x;
  const _Float16* A = side ? ga.A1 : ga.A0;
  const _Float16* Wt = side ? ga.Wt1 : ga.Wt0;
  _Float16* Z = side ? ga.Z1 : ga.Z0;
  const float* al = side ? ga.al1 : ga.al0;
  float* EL = side ? ga.EL1 : ga.EL0;
  const _Float16* wart = side ? ga.wart_s1 : ga.wart_s0;
  float* ER = side ? ga.ER_s1 : ga.ER_s0;
  const int K = ga.K, M = ga.M;
  int row0 = bid * 64;
  int wave = threadIdx.x >> 6;           // wave == head; cols wave*64..
  int lane = threadIdx.x & 63;
  int lr = lane & 15, kg = lane >> 4;
  int col0 = wave * 64;

  // stage A tile [row0..row0+64) x [k0..k0+64) into As[buf]; source pre-swizzled
  auto stage = [&](int buf, int k0) {
#pragma unroll
    for (int j = 0; j < 2; ++j) {
      int Lb = j * 4096 + wave * 1024;          // wave-uniform LDS byte base
      int L = Lb + lane * 16;                   // this lane's linear slot
      int r = L >> 7;                           // row in tile (128B per row)
      int kb = (L & 127) ^ ((r & 7) << 4);      // pre-swizzled source column byte
      int rg = row0 + r; rg = rg < M ? rg : M - 1;
      const char* gsrc = (const char*)A + ((size_t)rg * K + k0) * 2 + kb;
      char* ldst = (char*)(&As[buf][0]) + Lb;
      __builtin_amdgcn_global_load_lds(
          (const __attribute__((address_space(1))) unsigned int*)gsrc,
          (__attribute__((address_space(3))) unsigned int*)ldst, 16, 0, 0);
    }
  };

  f32x4 acc[4][4];
#pragma unroll
  for (int i = 0; i < 4; ++i)
#pragma unroll
    for (int j = 0; j < 4; ++j) acc[i][j] = (f32x4){0.f, 0.f, 0.f, 0.f};
  f32x4 acc_er[4];
#pragma unroll
  for (int i = 0; i < 4; ++i) acc_er[i] = (f32x4){0.f, 0.f, 0.f, 0.f};

  int nt = K >> 6;   // BK = 64
  stage(0, 0);
  __syncthreads();
  for (int t = 0; t < nt; ++t) {
    if (t + 1 < nt) stage((t + 1) & 1, (t + 1) * 64);
    const char* abuf = (const char*)(&As[t & 1][0]);
#pragma unroll
    for (int s = 0; s < 2; ++s) {
      int kk = t * 64 + s * 32 + kg * 8;
      f16x8 af[4], bfr[4];
#pragma unroll
      for (int mt = 0; mt < 4; ++mt) {
        int r = mt * 16 + lr;
        int cb = ((s << 6) | (kg << 4)) ^ ((r & 7) << 4);   // swizzled read
        af[mt] = *reinterpret_cast<const f16x8*>(abuf + r * 128 + cb);
      }
#pragma unroll
      for (int ct = 0; ct < 4; ++ct) {
        int c = col0 + ct * 16 + lr;
        bfr[ct] = *reinterpret_cast<const f16x8*>(Wt + (size_t)c * K + kk);
      }
#pragma unroll
      for (int mt = 0; mt < 4; ++mt)
#pragma unroll
        for (int ct = 0; ct < 4; ++ct)
          acc[mt][ct] = __builtin_amdgcn_mfma_f32_16x16x32_f16(af[mt], bfr[ct], acc[mt][ct], 0, 0, 0);
      if (wave == 0) {
        f16x8 eb = *reinterpret_cast<const f16x8*>(wart + lr * 256 + kk);
#pragma unroll
        for (int mt = 0; mt < 4; ++mt)
          acc_er[mt] = __builtin_amdgcn_mfma_f32_16x16x32_f16(af[mt], eb, acc_er[mt], 0, 0, 0);
      }
    }
    __syncthreads();
  }

  // C-write: col = lane&15, row = (lane>>4)*4 + reg
#pragma unroll
  for (int mt = 0; mt < 4; ++mt) {
#pragma unroll
    for (int r = 0; r < 4; ++r) {
      int row = row0 + mt * 16 + kg * 4 + r;
      if (row < M) {
#pragma unroll
        for (int ct = 0; ct < 4; ++ct) {
          int col = col0 + ct * 16 + lr;
          Z[(size_t)row * HF + col] = (_Float16)acc[mt][ct][r];
        }
      }
    }
  }
  // fused el epilogue: this wave's 64 cols == head(=wave)'s 64 dims
  float al4[4];
#pragma unroll
  for (int ct = 0; ct < 4; ++ct) al4[ct] = al[col0 + ct * 16 + lr];
#pragma unroll
  for (int mt = 0; mt < 4; ++mt) {
#pragma unroll
    for (int r = 0; r < 4; ++r) {
      float p = acc[mt][0][r] * al4[0] + acc[mt][1][r] * al4[1] +
                acc[mt][2][r] * al4[2] + acc[mt][3][r] * al4[3];
#pragma unroll
      for (int off = 1; off < 16; off <<= 1) p += __shfl_xor(p, off);
      int row = row0 + mt * 16 + kg * 4 + r;
      if (lr == 0 && row < M) EL[(size_t)row * 4 + wave] = p;
    }
  }
  // er epilogue (wave 0 only): er[row][h=lr<4]
  if (wave == 0 && lr < 4) {
#pragma unroll
    for (int mt = 0; mt < 4; ++mt) {
#pragma unroll
      for (int r = 0; r < 4; ++r) {
        int row = row0 + mt * 16 + kg * 4 + r;
        if (row < M) ER[(size_t)row * 4 + lr] = acc_er[mt][r];
      }
    }
  }
}

// ---------- CSR build (both relations per dispatch) ----------
__global__ __launch_bounds__(256) void k_hist2(const int* __restrict__ d0, const int* __restrict__ d1,
                                               int* __restrict__ c0, int* __restrict__ c1) {
  int t = blockIdx.x * 256 + threadIdx.x;
  if (t < NE) atomicAdd(&c0[d0[t]], 1);
  else if (t < 2 * NE) atomicAdd(&c1[d1[t - NE]], 1);
}

__global__ __launch_bounds__(1024) void k_scan1_2(const int* __restrict__ c0, const int* __restrict__ c1,
                                                  int* __restrict__ rp0, int* __restrict__ rp1,
                                                  int* __restrict__ b0, int* __restrict__ b1, int nscan) {
  __shared__ int tmp[1024];
  int rel = blockIdx.x >= nscan;
  int blk = rel ? blockIdx.x - nscan : blockIdx.x;
  const int* counts = rel ? c1 : c0;
  int* rp = rel ? rp1 : rp0;
  int* bsum = rel ? b1 : b0;
  int i = blk * 1024 + threadIdx.x;
  int v = (i < NN) ? counts[i] : 0;
  tmp[threadIdx.x] = v;
  __syncthreads();
  for (int off = 1; off < 1024; off <<= 1) {
    int t = (threadIdx.x >= off) ? tmp[threadIdx.x - off] : 0;
    __syncthreads();
    tmp[threadIdx.x] += t;
    __syncthreads();
  }
  if (i < NN) rp[i] = tmp[threadIdx.x] - v;  // block-local exclusive
  if (threadIdx.x == 1023) bsum[blk] = tmp[1023];
}

__global__ __launch_bounds__(128) void k_scan2_2(int* __restrict__ b0, int* __restrict__ b1, int nb) {
  int rel = threadIdx.x >> 6;
  int l = threadIdx.x & 63;
  int* bsum = rel ? b1 : b0;
  int orig = (l < nb) ? bsum[l] : 0;
  int v = orig;
#pragma unroll
  for (int off = 1; off < 64; off <<= 1) {
    int t = __shfl_up(v, off);
    if (l >= off) v += t;
  }
  if (l < nb) bsum[l] = v - orig;  // exclusive
}

__global__ __launch_bounds__(1024) void k_scan3_2(int* __restrict__ rp0, int* __restrict__ rp1,
                                                  const int* __restrict__ b0, const int* __restrict__ b1,
                                                  int nscan) {
  int rel = blockIdx.x >= nscan;
  int blk = rel ? blockIdx.x - nscan : blockIdx.x;
  int* rp = rel ? rp1 : rp0;
  const int* bsum = rel ? b1 : b0;
  int i = blk * 1024 + threadIdx.x;
  if (i < NN) rp[i] += bsum[blk];
  if (i == 0) rp[NN] = NE;
}

__global__ __launch_bounds__(256) void k_scatter2(
    const int* __restrict__ s0, const int* __restrict__ d0,
    const int* __restrict__ s1, const int* __restrict__ d1,
    const int* __restrict__ rp0, const int* __restrict__ rp1,
    int* __restrict__ f0, int* __restrict__ f1,
    int* __restrict__ cs0, int* __restrict__ cs1) {
  int t = blockIdx.x * 256 + threadIdx.x;
  if (t < NE) {
    int d = d0[t];
    int pos = rp0[d] + atomicAdd(&f0[d], 1);
    cs0[pos] = s0[t];
  } else if (t < 2 * NE) {
    int e = t - NE;
    int d = d1[e];
    int pos = rp1[d] + atomicAdd(&f1[d], 1);
    cs1[pos] = s1[e];
  }
}

// ---------- degree-sort permutation (64 buckets, both relations, LDS-privatized) ----------
__global__ __launch_bounds__(256) void k_deghist2(const int* __restrict__ rp0,
                                                  const int* __restrict__ rp1,
                                                  int* __restrict__ dh) {  // dh[2][64]
  __shared__ int h[128];
  if (threadIdx.x < 128) h[threadIdx.x] = 0;
  __syncthreads();
  int t = blockIdx.x * 256 + threadIdx.x;
  if (t < NN) {
    atomicAdd(&h[min(rp0[t + 1] - rp0[t], 63)], 1);
  } else if (t < 2 * NN) {
    int n = t - NN;
    atomicAdd(&h[64 + min(rp1[n + 1] - rp1[n], 63)], 1);
  }
  __syncthreads();
  if (threadIdx.x < 128) {
    int v = h[threadIdx.x];
    if (v) atomicAdd(&dh[threadIdx.x], v);
  }
}

__global__ __launch_bounds__(128) void k_degscan(const int* __restrict__ dh, int* __restrict__ dofs) {
  int rel = threadIdx.x >> 6;
  int l = threadIdx.x & 63;
  int orig = dh[rel * 64 + l];
  int v = orig;
#pragma unroll
  for (int off = 1; off < 64; off <<= 1) {
    int t = __shfl_up(v, off);
    if (l >= off) v += t;
  }
  dofs[rel * 64 + l] = v - orig;  // exclusive
}

__global__ __launch_bounds__(256) void k_permscatter2(const int* __restrict__ rp0,
                                                      const int* __restrict__ rp1,
                                                      const int* __restrict__ dofs,
                                                      int* __restrict__ dfill,
                                                      int* __restrict__ perm0,
                                                      int* __restrict__ perm1) {
  __shared__ int lcnt[128];
  __shared__ int lbase[128];
  if (threadIdx.x < 128) lcnt[threadIdx.x] = 0;
  __syncthreads();
  int t = blockIdx.x * 256 + threadIdx.x;
  int bucket = -1, node = 0, rank = 0, rel = 0;
  if (t < NN) {
    node = t; rel = 0;
    bucket = min(rp0[t + 1] - rp0[t], 63);
    rank = atomicAdd(&lcnt[bucket], 1);
  } else if (t < 2 * NN) {
    node = t - NN; rel = 1;
    bucket = 64 + min(rp1[node + 1] - rp1[node], 63);
    rank = atomicAdd(&lcnt[bucket], 1);
  }
  __syncthreads();
  if (threadIdx.x < 128) {
    int v = lcnt[threadIdx.x];
    lbase[threadIdx.x] = v ? atomicAdd(&dfill[threadIdx.x], v) : 0;
  }
  __syncthreads();
  if (bucket >= 0) {
    int pos = dofs[bucket] + lbase[bucket] + rank;
    if (rel == 0) perm0[pos] = node;
    else perm1[pos] = node;
  }
}

__device__ __forceinline__ float pick_h(float4 v, int h) {
  float r = v.x;
  r = (h == 1) ? v.y : r;
  r = (h == 2) ? v.z : r;
  r = (h == 3) ? v.w : r;
  return r;
}

// ---------- fused GAT aggregation, both relations per dispatch, degree-sorted ----------
// pass B uses v_dot2_f32_f16: two edges per step, exact f16x f16 products, f32 accum.
template <typename OT>
__global__ __launch_bounds__(256) void k_agg2(
    const int* __restrict__ rpA, const int* __restrict__ csA, const int* __restrict__ permA,
    const float* __restrict__ elA, const float* __restrict__ erA,
    const _Float16* __restrict__ ZA, const float* __restrict__ bA, OT* __restrict__ oA,
    const int* __restrict__ rpB, const int* __restrict__ csB, const int* __restrict__ permB,
    const float* __restrict__ elB, const float* __restrict__ erB,
    const _Float16* __restrict__ ZB, const float* __restrict__ bB, OT* __restrict__ oB) {
  __shared__ float exs[4][256];
  __shared__ int ssrc[4][64];
  int nb = (NN + 3) / 4;
  int rel = blockIdx.x >= nb;
  int bid = rel ? blockIdx.x - nb : blockIdx.x;
  const int* rp = rel ? rpB : rpA;
  const int* csrc = rel ? csB : csA;
  const float* el = rel ? elB : elA;
  const float* er = rel ? erB : erA;
  const _Float16* Z = rel ? ZB : ZA;
  const float* bias = rel ? bB : bA;
  OT* out = rel ? oB : oA;

  int wv = threadIdx.x >> 6;
  int gid = bid * 4 + wv;
  if (gid >= NN) return;
  int wid = (rel ? permB : permA)[gid];
  int lane = threadIdx.x & 63;
  int half = lane >> 5, l5 = lane & 31;
  int c0 = l5 * 8;      // 8 cols per lane (halves cover full row)
  int h = l5 >> 3;      // head for cols c0..c0+7
  int beg = rp[wid], end = rp[wid + 1];
  int deg = end - beg;

  if (deg == 0) {
    if (half == 0) {
      float4 b0 = *reinterpret_cast<const float4*>(bias + c0);
      float4 b1 = *reinterpret_cast<const float4*>(bias + c0 + 4);
      if constexpr (std::is_same<OT, float>::value) {
        float4* op = reinterpret_cast<float4*>(out + (size_t)wid * HF + c0);
        op[0] = b0; op[1] = b1;
      } else {
        f16x8 o = {(_Float16)b0.x, (_Float16)b0.y, (_Float16)b0.z, (_Float16)b0.w,
                   (_Float16)b1.x, (_Float16)b1.y, (_Float16)b1.z, (_Float16)b1.w};
        *reinterpret_cast<f16x8*>(out + (size_t)wid * HF + c0) = o;
      }
    }
    return;
  }

  if (deg <= 64) {
    // ---- pass A: lane i owns edge i ----
    int s = 0;
    float4 x = {-1e30f, -1e30f, -1e30f, -1e30f};
    float4 b = *reinterpret_cast<const float4*>(er + (size_t)wid * 4);
    if (lane < deg) {
      s = csrc[beg + lane];
      float4 a = reinterpret_cast<const float4*>(el)[s];
      x.x = a.x + b.x; x.x = x.x >= 0.f ? x.x : 0.2f * x.x;
      x.y = a.y + b.y; x.y = x.y >= 0.f ? x.y : 0.2f * x.y;
      x.z = a.z + b.z; x.z = x.z >= 0.f ? x.z : 0.2f * x.z;
      x.w = a.w + b.w; x.w = x.w >= 0.f ? x.w : 0.2f * x.w;
    }
    float4 m = x;
#pragma unroll
    for (int off = 32; off > 0; off >>= 1) {
      m.x = fmaxf(m.x, __shfl_xor(m.x, off));
      m.y = fmaxf(m.y, __shfl_xor(m.y, off));
      m.z = fmaxf(m.z, __shfl_xor(m.z, off));
      m.w = fmaxf(m.w, __shfl_xor(m.w, off));
    }
    float4 ex = {0.f, 0.f, 0.f, 0.f};
    if (lane < deg) {
      ex.x = __expf(x.x - m.x);
      ex.y = __expf(x.y - m.y);
      ex.z = __expf(x.z - m.z);
      ex.w = __expf(x.w - m.w);
    }
    float4 sm = ex;
#pragma unroll
    for (int off = 32; off > 0; off >>= 1) {
      sm.x += __shfl_xor(sm.x, off);
      sm.y += __shfl_xor(sm.y, off);
      sm.z += __shfl_xor(sm.z, off);
      sm.w += __shfl_xor(sm.w, off);
    }
    float inv = 1.0f / pick_h(sm, h);
    if (lane < deg) {
      *reinterpret_cast<float4*>(&exs[wv][lane * 4]) = ex;
      ssrc[wv][lane] = s;
    }
    // ---- pass B: halves own alternate edges; dot2 pairs two edges per step ----
    float a8[8] = {0.f, 0.f, 0.f, 0.f, 0.f, 0.f, 0.f, 0.f};
    int j = half;
#define PAIR_STEP(J)                                                        \
    {                                                                       \
      int s1 = ssrc[wv][(J)];                                               \
      int s2 = ssrc[wv][(J) + 2];                                           \
      float w1 = exs[wv][(J) * 4 + h];                                      \
      float w2 = exs[wv][((J) + 2) * 4 + h];                                \
      f16x8 z1 = *reinterpret_cast<const f16x8*>(Z + (size_t)s1 * HF + c0); \
      f16x8 z2 = *reinterpret_cast<const f16x8*>(Z + (size_t)s2 * HF + c0); \
      f16x2 w12 = {(_Float16)w1, (_Float16)w2};                             \
      _Pragma("unroll")                                                     \
      for (int q = 0; q < 8; ++q) {                                         \
        f16x2 p = {z1[q], z2[q]};                                           \
        a8[q] = __builtin_amdgcn_fdot2(p, w12, a8[q], false);               \
      }                                                                     \
    }
#define ONE_STEP(J)                                                         \
    {                                                                       \
      int sj = ssrc[wv][(J)];                                               \
      float wj = exs[wv][(J) * 4 + h];                                      \
      f16x8 z = *reinterpret_cast<const f16x8*>(Z + (size_t)sj * HF + c0);  \
      _Pragma("unroll")                                                     \
      for (int q = 0; q < 8; ++q) a8[q] += wj * (float)z[q];                \
    }
    for (; j + 6 < deg; j += 8) { PAIR_STEP(j); PAIR_STEP(j + 4); }
    for (; j + 2 < deg; j += 4) { PAIR_STEP(j); }
    for (; j < deg; j += 2) { ONE_STEP(j); }
#undef PAIR_STEP
#undef ONE_STEP
#pragma unroll
    for (int q = 0; q < 8; ++q) a8[q] += __shfl_xor(a8[q], 32);
    if (half == 0) {
      float4 b0 = *reinterpret_cast<const float4*>(bias + c0);
      float4 b1 = *reinterpret_cast<const float4*>(bias + c0 + 4);
      float r0 = a8[0] * inv + b0.x, r1 = a8[1] * inv + b0.y;
      float r2 = a8[2] * inv + b0.z, r3 = a8[3] * inv + b0.w;
      float r4 = a8[4] * inv + b1.x, r5 = a8[5] * inv + b1.y;
      float r6 = a8[6] * inv + b1.z, r7 = a8[7] * inv + b1.w;
      if constexpr (std::is_same<OT, float>::value) {
        float4* op = reinterpret_cast<float4*>(out + (size_t)wid * HF + c0);
        op[0] = (float4){r0, r1, r2, r3};
        op[1] = (float4){r4, r5, r6, r7};
      } else {
        f16x8 o = {(_Float16)r0, (_Float16)r1, (_Float16)r2, (_Float16)r3,
                   (_Float16)r4, (_Float16)r5, (_Float16)r6, (_Float16)r7};
        *reinterpret_cast<f16x8*>(out + (size_t)wid * HF + c0) = o;
      }
    }
    return;
  }

  // ---- rare fallback (deg > 64): uniform two-pass, full-wave f16x4 mapping ----
  {
    int c4 = lane * 4;
    int h4 = lane >> 4;
    float4 b = *reinterpret_cast<const float4*>(er + (size_t)wid * 4);
    float4 m = {-1e30f, -1e30f, -1e30f, -1e30f};
    for (int e = beg; e < end; ++e) {
      int s = csrc[e];
      float4 a = reinterpret_cast<const float4*>(el)[s];
      float4 x;
      x.x = a.x + b.x; x.x = x.x >= 0.f ? x.x : 0.2f * x.x;
      x.y = a.y + b.y; x.y = x.y >= 0.f ? x.y : 0.2f * x.y;
      x.z = a.z + b.z; x.z = x.z >= 0.f ? x.z : 0.2f * x.z;
      x.w = a.w + b.w; x.w = x.w >= 0.f ? x.w : 0.2f * x.w;
      m.x = fmaxf(m.x, x.x); m.y = fmaxf(m.y, x.y);
      m.z = fmaxf(m.z, x.z); m.w = fmaxf(m.w, x.w);
    }
    float4 sm = {0.f, 0.f, 0.f, 0.f};
    float4 acc = {0.f, 0.f, 0.f, 0.f};
    for (int e = beg; e < end; ++e) {
      int s = csrc[e];
      float4 a = reinterpret_cast<const float4*>(el)[s];
      float4 x;
      x.x = a.x + b.x; x.x = x.x >= 0.f ? x.x : 0.2f * x.x;
      x.y = a.y + b.y; x.y = x.y >= 0.f ? x.y : 0.2f * x.y;
      x.z = a.z + b.z; x.z = x.z >= 0.f ? x.z : 0.2f * x.z;
      x.w = a.w + b.w; x.w = x.w >= 0.f ? x.w : 0.2f * x.w;
      float4 exv;
      exv.x = __expf(x.x - m.x); exv.y = __expf(x.y - m.y);
      exv.z = __expf(x.z - m.z); exv.w = __expf(x.w - m.w);
      sm.x += exv.x; sm.y += exv.y; sm.z += exv.z; sm.w += exv.w;
      float w0 = pick_h(exv, h4);
      f16x4 z0 = *reinterpret_cast<const f16x4*>(Z + (size_t)s * HF + c4);
      acc.x += w0 * (float)z0.x;
      acc.y += w0 * (float)z0.y;
      acc.z += w0 * (float)z0.z;
      acc.w += w0 * (float)z0.w;
    }
    float inv = 1.0f / pick_h(sm, h4);
    float4 bv = *reinterpret_cast<const float4*>(bias + c4);
    float r0 = acc.x * inv + bv.x, r1 = acc.y * inv + bv.y;
    float r2 = acc.z * inv + bv.z, r3 = acc.w * inv + bv.w;
    if constexpr (std::is_same<OT, float>::value) {
      *reinterpret_cast<float4*>(out + (size_t)wid * HF + c4) = (float4){r0, r1, r2, r3};
    } else {
      f16x4 o = {(_Float16)r0, (_Float16)r1, (_Float16)r2, (_Float16)r3};
      *reinterpret_cast<f16x4*>(out + (size_t)wid * HF + c4) = o;
    }
  }
}

// ---------- batchnorm stats, both sides per dispatch ----------
__global__ __launch_bounds__(256) void k_bn_stats2(const _Float16* __restrict__ XU,
                                                   const _Float16* __restrict__ XI,
                                                   float* __restrict__ su, float* __restrict__ qu,
                                                   float* __restrict__ si, float* __restrict__ qi) {
  int rel = blockIdx.x >> 9;  // grid = 1024
  int blk = blockIdx.x & 511;
  const _Float16* X = rel ? XI : XU;
  float* sums = rel ? si : su;
  float* sqs = rel ? qi : qu;
  int c = threadIdx.x;
  float s = 0.f, q = 0.f;
  for (int r = blk; r < NN; r += 512) {
    float v = (float)X[(size_t)r * HF + c];
    s += v;
    q += v * v;
  }
  atomicAdd(&sums[c], s);
  atomicAdd(&sqs[c], q);
}

// ---------- batchnorm apply, both sides per dispatch (RAW16 -> H16) ----------
__global__ __launch_bounds__(256) void k_bn_apply2(
    const _Float16* __restrict__ XU, const _Float16* __restrict__ XI,
    const float* __restrict__ su, const float* __restrict__ qu,
    const float* __restrict__ si, const float* __restrict__ qi,
    const float* __restrict__ gU, const float* __restrict__ btU,
    const float* __restrict__ gI, const float* __restrict__ btI,
    _Float16* __restrict__ YU, _Float16* __restrict__ YI, int act) {
  const int nb = NN * HF / 8 / 256;  // 6250
  int rel = blockIdx.x >= nb;
  int bid = rel ? blockIdx.x - nb : blockIdx.x;
  const _Float16* X = rel ? XI : XU;
  const float* sums = rel ? si : su;
  const float* sqs = rel ? qi : qu;
  const float* g = rel ? gI : gU;
  const float* bt = rel ? btI : btU;
  _Float16* Y = rel ? YI : YU;
  int gid = bid * 256 + threadIdx.x;
  int i0 = gid * 8;
  int c0 = i0 & 255;
  const float invN = 1.0f / NN;
  f16x8 xv = *reinterpret_cast<const f16x8*>(X + i0);
  float4 s0 = *reinterpret_cast<const float4*>(sums + c0);
  float4 s1 = *reinterpret_cast<const float4*>(sums + c0 + 4);
  float4 q0 = *reinterpret_cast<const float4*>(sqs + c0);
  float4 q1 = *reinterpret_cast<const float4*>(sqs + c0 + 4);
  float4 g0 = *reinterpret_cast<const float4*>(g + c0);
  float4 g1 = *reinterpret_cast<const float4*>(g + c0 + 4);
  float4 b0 = *reinterpret_cast<const float4*>(bt + c0);
  float4 b1 = *reinterpret_cast<const float4*>(bt + c0 + 4);
  float sa[8] = {s0.x, s0.y, s0.z, s0.w, s1.x, s1.y, s1.z, s1.w};
  float qa[8] = {q0.x, q0.y, q0.z, q0.w, q1.x, q1.y, q1.z, q1.w};
  float ga[8] = {g0.x, g0.y, g0.z, g0.w, g1.x, g1.y, g1.z, g1.w};
  float ba[8] = {b0.x, b0.y, b0.z, b0.w, b1.x, b1.y, b1.z, b1.w};
  f16x8 o;
#pragma unroll
  for (int j = 0; j < 8; ++j) {
    float mu = sa[j] * invN;
    float var = qa[j] * invN - mu * mu;
    float sc = rsqrtf(var + 1e-5f) * ga[j];
    float v = ((float)xv[j] - mu) * sc + ba[j];
    v = act ? tanhf(v) : (v >= 0.f ? v : 0.01f * v);
    o[j] = (_Float16)v;
  }
  *reinterpret_cast<f16x8*>(Y + i0) = o;
}

extern "C" void kernel_launch(void* const* d_in, const int* in_sizes, int n_in,
                              void* d_out, int out_size, void* d_ws, size_t ws_size,
                              hipStream_t stream) {
  (void)in_sizes; (void)n_in; (void)out_size; (void)ws_size;
  const float* x_user = (const float*)d_in[0];
  const float* x_item = (const float*)d_in[1];
  const int* ui_src = (const int*)d_in[2];
  const int* ui_dst = (const int*)d_in[3];
  const int* iu_src = (const int*)d_in[4];
  const int* iu_dst = (const int*)d_in[5];
  const float *Wp[4], *alp[4], *arp[4], *bp[4];
  for (int l = 0; l < 4; ++l) {
    Wp[l]  = (const float*)d_in[6 + 4 * l];
    alp[l] = (const float*)d_in[7 + 4 * l];
    arp[l] = (const float*)d_in[8 + 4 * l];
    bp[l]  = (const float*)d_in[9 + 4 * l];
  }
  const float* bng = (const float*)d_in[22];
  const float* bnb = (const float*)d_in[23];

  char* w = (char*)d_ws;
  auto alloc = [&](size_t bytes) -> void* {
    void* p = (void*)w;
    w += (bytes + 255) & ~(size_t)255;
    return p;
  };
  _Float16* XU16 = (_Float16*)alloc((size_t)NN * 128 * 2);
  _Float16* XI16 = (_Float16*)alloc((size_t)NN * 128 * 2);
  _Float16* H16U = (_Float16*)alloc((size_t)NN * HF * 2);
  _Float16* H16I = (_Float16*)alloc((size_t)NN * HF * 2);
  _Float16* Z0 = (_Float16*)alloc((size_t)NN * HF * 2);
  _Float16* Z1 = (_Float16*)alloc((size_t)NN * HF * 2);
  _Float16* RAW16U = (_Float16*)alloc((size_t)NN * HF * 2);
  _Float16* RAW16I = (_Float16*)alloc((size_t)NN * HF * 2);
  float* EL0 = (float*)alloc((size_t)NN * 4 * 4);
  float* ER0 = (float*)alloc((size_t)NN * 4 * 4);
  float* EL1 = (float*)alloc((size_t)NN * 4 * 4);
  float* ER1 = (float*)alloc((size_t)NN * 4 * 4);
  _Float16* WT = (_Float16*)alloc((size_t)8 * 65536 * 2);
  _Float16* WART = (_Float16*)alloc((size_t)8 * 4096 * 2);  // [8][16][256] fp16
  int* rp_ui = (int*)alloc((size_t)(NN + 1) * 4);
  int* rp_iu = (int*)alloc((size_t)(NN + 1) * 4);
  int* csrc_ui = (int*)alloc((size_t)NE * 4);
  int* csrc_iu = (int*)alloc((size_t)NE * 4);
  int* perm_ui = (int*)alloc((size_t)NN * 4);
  int* perm_iu = (int*)alloc((size_t)NN * 4);
  int* counts = (int*)alloc((size_t)4 * NN * 4);  // counts_ui | counts_iu | fill_ui | fill_iu
  int* bsum_ui = (int*)alloc((size_t)64 * 4);
  int* bsum_iu = (int*)alloc((size_t)64 * 4);
  int* degws = (int*)alloc((size_t)384 * 4);      // dh[128] | dofs[128] | dfill[128]
  float* stats = (float*)alloc((size_t)6 * 512 * 4);

  int* counts_ui = counts;
  int* counts_iu = counts + NN;
  int* fill_ui = counts + 2 * NN;
  int* fill_iu = counts + 3 * NN;
  int* dh = degws;
  int* dofs = degws + 128;
  int* dfill = degws + 256;

  hipMemsetAsync(counts, 0, (size_t)4 * NN * 4, stream);
  hipMemsetAsync(stats, 0, (size_t)6 * 512 * 4, stream);
  hipMemsetAsync(WART, 0, (size_t)8 * 4096 * 2, stream);
  hipMemsetAsync(degws, 0, (size_t)384 * 4, stream);

  // input conversion (one dispatch)
  int n4 = NN * 128 / 4;
  k_tofp16_2<<<(2 * n4 + 255) / 256, 256, 0, stream>>>(x_user, x_item, XU16, XI16, n4);

  // all weight transposes (one dispatch)
  TArgs ta;
  int cum = 0;
  for (int l = 0; l < 4; ++l) {
    int K = (l == 0) ? 128 : 256;
    for (int r = 0; r < 2; ++r) {
      int s = l * 2 + r;
      ta.W[s] = Wp[l] + (size_t)r * K * HF;
      ta.dst[s] = WT + (size_t)s * 65536;
      ta.K[s] = K;
      ta.cum[s] = cum;
      cum += K * 256;
    }
  }
  ta.cum[8] = cum;
  k_transpose_all<<<(cum + 255) / 256, 256, 0, stream>>>(ta);

  // all W.ar attn tables, fp16 padded (one dispatch)
  k_makeattn_all<<<(8 * 256 * 4 + 255) / 256, 256, 0, stream>>>(
      Wp[0], Wp[1], Wp[2], Wp[3], arp[0], arp[1], arp[2], arp[3], WART);

  // CSR build (both relations per dispatch)
  int egrid2 = (2 * NE + 255) / 256;
  int nscan = (NN + 1023) / 1024;
  k_hist2<<<egrid2, 256, 0, stream>>>(ui_dst, iu_dst, counts_ui, counts_iu);
  k_scan1_2<<<2 * nscan, 1024, 0, stream>>>(counts_ui, counts_iu, rp_ui, rp_iu, bsum_ui, bsum_iu, nscan);
  k_scan2_2<<<1, 128, 0, stream>>>(bsum_ui, bsum_iu, nscan);
  k_scan3_2<<<2 * nscan, 1024, 0, stream>>>(rp_ui, rp_iu, bsum_ui, bsum_iu, nscan);
  k_scatter2<<<egrid2, 256, 0, stream>>>(ui_src, ui_dst, iu_src, iu_dst, rp_ui, rp_iu,
                                         fill_ui, fill_iu, csrc_ui, csrc_iu);

  // degree-sorted permutations (both relations, LDS-privatized atomics)
  int ngrid2 = (2 * NN + 255) / 256;
  k_deghist2<<<ngrid2, 256, 0, stream>>>(rp_ui, rp_iu, dh);
  k_degscan<<<1, 128, 0, stream>>>(dh, dofs);
  k_permscatter2<<<ngrid2, 256, 0, stream>>>(rp_ui, rp_iu, dofs, dfill, perm_ui, perm_iu);

  int agrid = (NN + 3) / 4;
  int nrow = (NN + 63) / 64;
  float* out_user = (float*)d_out;
  float* out_item = (float*)d_out + (size_t)NN * HF;

  for (int l = 0; l < 4; ++l) {
    int K = (l == 0) ? 128 : 256;
    const _Float16* Au = (l == 0) ? XU16 : H16U;
    const _Float16* Ai = (l == 0) ? XI16 : H16I;

    // GEMM pair: Z0 = hu@W0 (+el0, +er1), Z1 = hi@W1 (+el1, +er0)
    GArgs ga;
    ga.A0 = Au; ga.A1 = Ai;
    ga.Wt0 = WT + (size_t)(l * 2 + 0) * 65536;
    ga.Wt1 = WT + (size_t)(l * 2 + 1) * 65536;
    ga.Z0 = Z0; ga.Z1 = Z1;
    ga.al0 = alp[l] + 0; ga.al1 = alp[l] + 256;
    ga.EL0 = EL0; ga.EL1 = EL1;
    ga.wart_s0 = WART + (size_t)(l * 2 + 1) * 4096;  // side0 (A=hu) -> er1 = hu.(W1.ar1)
    ga.wart_s1 = WART + (size_t)(l * 2 + 0) * 4096;  // side1 (A=hi) -> er0 = hi.(W0.ar0)
    ga.ER_s0 = ER1; ga.ER_s1 = ER0;
    ga.M = NN; ga.K = K;
    k_gemm5<<<2 * nrow, 256, 0, stream>>>(ga);

    // aggregation pair: u->i (dst items, Z0) and i->u (dst users, Z1)
    if (l < 3)
      k_agg2<_Float16><<<2 * agrid, 256, 0, stream>>>(
          rp_ui, csrc_ui, perm_ui, EL0, ER0, Z0, bp[l] + 0, RAW16I,
          rp_iu, csrc_iu, perm_iu, EL1, ER1, Z1, bp[l] + 256, RAW16U);
    else
      k_agg2<float><<<2 * agrid, 256, 0, stream>>>(
          rp_ui, csrc_ui, perm_ui, EL0, ER0, Z0, bp[l] + 0, out_item,
          rp_iu, csrc_iu, perm_iu, EL1, ER1, Z1, bp[l] + 256, out_user);

    if (l < 3) {
      int act = (l == 2) ? 1 : 0;
      float* su = stats + (size_t)(l * 2 + 0) * 512;
      float* si = stats + (size_t)(l * 2 + 1) * 512;
      k_bn_stats2<<<1024, 256, 0, stream>>>(RAW16U, RAW16I, su, su + 256, si, si + 256);
      k_bn_apply2<<<2 * (NN * HF / 8 / 256), 256, 0, stream>>>(
          RAW16U, RAW16I, su, su + 256, si, si + 256,
          bng + (size_t)(l * 2 + 0) * 256, bnb + (size_t)(l * 2 + 0) * 256,
          bng + (size_t)(l * 2 + 1) * 256, bnb + (size_t)(l * 2 + 1) * 256,
          H16U, H16I, act);
    }
  }
}

// Round 15
// 953.288 us; speedup vs baseline: 1.4049x; 1.0226x over previous
//
#include <hip/hip_runtime.h>
#include <hip/hip_bf16.h>
#include <type_traits>

#define NN 50000     // nodes per side (users == items == 50000)
#define NE 600000    // edges per relation
#define HF 256       // hidden features

typedef float f32x4 __attribute__((ext_vector_type(4)));
typedef _Float16 f16x8 __attribute__((ext_vector_type(8)));
typedef _Float16 f16x4 __attribute__((ext_vector_type(4)));
typedef _Float16 f16x2 __attribute__((ext_vector_type(2)));

// ---------- fp32 -> fp16 convert, both inputs in one dispatch ----------
__global__ __launch_bounds__(256) void k_tofp16_2(const float* __restrict__ A,
                                                  const float* __restrict__ B,
                                                  _Float16* __restrict__ OA,
                                                  _Float16* __restrict__ OB, int n4) {
  int i = blockIdx.x * 256 + threadIdx.x;
  const float* X = (i < n4) ? A : B;
  _Float16* Y = (i < n4) ? OA : OB;
  int j = (i < n4) ? i : i - n4;
  if (j < n4) {
    float4 v = reinterpret_cast<const float4*>(X)[j];
    f16x4 o = {(_Float16)v.x, (_Float16)v.y, (_Float16)v.z, (_Float16)v.w};
    reinterpret_cast<f16x4*>(Y)[j] = o;
  }
}

// ---------- all 8 W[K][256] -> Wt[256][K] transposes in one dispatch ----------
struct TArgs {
  const float* W[8];
  _Float16* dst[8];
  int K[8];
  int cum[9];
};
__global__ __launch_bounds__(256) void k_transpose_all(TArgs t) {
  int idx = blockIdx.x * 256 + threadIdx.x;
#pragma unroll
  for (int s = 0; s < 8; ++s) {
    if (idx >= t.cum[s] && idx < t.cum[s + 1]) {
      int local = idx - t.cum[s];
      int K = t.K[s];
      int k = local >> 8;
      int n = local & 255;
      t.dst[s][(size_t)n * K + k] = (_Float16)t.W[s][local];
    }
  }
}

// ---------- all W.ar attn tables, fp16 [16][256]-padded, in one dispatch ----------
__global__ __launch_bounds__(256) void k_makeattn_all(
    const float* __restrict__ W1, const float* __restrict__ W2,
    const float* __restrict__ W3, const float* __restrict__ W4,
    const float* __restrict__ ar1, const float* __restrict__ ar2,
    const float* __restrict__ ar3, const float* __restrict__ ar4,
    _Float16* __restrict__ wart) {   // [8][16][256] fp16, cols 4..15 stay zero
  int idx = blockIdx.x * 256 + threadIdx.x;
  if (idx >= 8 * 256 * 4) return;
  int h = idx & 3;
  int k = (idx >> 2) & 255;
  int s = idx >> 10;  // l*2+r
  int l = s >> 1, r = s & 1;
  int K = (l == 0) ? 128 : 256;
  if (k >= K) return;
  const float* W = (l == 0 ? W1 : l == 1 ? W2 : l == 2 ? W3 : W4) + (size_t)r * K * 256;
  const float* a = (l == 0 ? ar1 : l == 1 ? ar2 : l == 2 ? ar3 : ar4) + r * 256 + h * 64;
  const float* wrow = W + (size_t)k * 256 + h * 64;
  float sum = 0.f;
#pragma unroll 8
  for (int d = 0; d < 64; ++d) sum += wrow[d] * a[d];
  wart[(size_t)s * 4096 + h * 256 + k] = (_Float16)sum;
}

// ---------- GEMM v5b: 64x256 tile, LDS-staged A (swizzled) dbuf, fused el + er(MFMA) ----------
struct GArgs {
  const _Float16* A0; const _Float16* A1;     // post-BN activations
  const _Float16* Wt0; const _Float16* Wt1;
  _Float16* Z0; _Float16* Z1;
  const float* al0; const float* al1;
  float* EL0; float* EL1;
  const _Float16* wart_s0; const _Float16* wart_s1;  // [16][256] fp16 W.ar tables
  float* ER_s0; float* ER_s1;                 // side0 -> ER1, side1 -> ER0
  int M, K;
};

__global__ __launch_bounds__(256) void k_gemm5(GArgs ga) {
  __shared__ _Float16 As[2][64 * 64];    // 2 x 8 KB double buffer
  const int nrow = (NN + 63) / 64;       // 782
  int side = blockIdx.x >= nrow;
  int bid = side ? blockIdx.x - nrow : blockIdx.x;
  const _Float16* A = side ? ga.A1 : ga.A0;
  const _Float16* Wt = side ? ga.Wt1 : ga.Wt0;
  _Float16* Z = side ? ga.Z1 : ga.Z0;
  const float* al = side ? ga.al1 : ga.al0;
  float* EL = side ? ga.EL1 : ga.EL0;
  const _Float16* wart = side ? ga.wart_s1 : ga.wart_s0;
  float* ER = side ? ga.ER_s1 : ga.ER_s0;
  const int K = ga.K, M = ga.M;
  int row0 = bid * 64;
  int wave = threadIdx.x >> 6;           // wave == head; cols wave*64..
  int lane = threadIdx.x & 63;
  int lr = lane & 15, kg = lane >> 4;
  int col0 = wave * 64;

  // stage A tile [row0..row0+64) x [k0..k0+64) into As[buf]; source pre-swizzled
  auto stage = [&](int buf, int k0) {
#pragma unroll
    for (int j = 0; j < 2; ++j) {
      int Lb = j * 4096 + wave * 1024;          // wave-uniform LDS byte base
      int L = Lb + lane * 16;                   // this lane's linear slot
      int r = L >> 7;                           // row in tile (128B per row)
      int kb = (L & 127) ^ ((r & 7) << 4);      // pre-swizzled source column byte
      int rg = row0 + r; rg = rg < M ? rg : M - 1;
      const char* gsrc = (const char*)A + ((size_t)rg * K + k0) * 2 + kb;
      char* ldst = (char*)(&As[buf][0]) + Lb;
      __builtin_amdgcn_global_load_lds(
          (const __attribute__((address_space(1))) unsigned int*)gsrc,
          (__attribute__((address_space(3))) unsigned int*)ldst, 16, 0, 0);
    }
  };

  f32x4 acc[4][4];
#pragma unroll
  for (int i = 0; i < 4; ++i)
#pragma unroll
    for (int j = 0; j < 4; ++j) acc[i][j] = (f32x4){0.f, 0.f, 0.f, 0.f};
  f32x4 acc_er[4];
#pragma unroll
  for (int i = 0; i < 4; ++i) acc_er[i] = (f32x4){0.f, 0.f, 0.f, 0.f};

  int nt = K >> 6;   // BK = 64
  stage(0, 0);
  __syncthreads();
  for (int t = 0; t < nt; ++t) {
    if (t + 1 < nt) stage((t + 1) & 1, (t + 1) * 64);
    const char* abuf = (const char*)(&As[t & 1][0]);
#pragma unroll
    for (int s = 0; s < 2; ++s) {
      int kk = t * 64 + s * 32 + kg * 8;
      f16x8 af[4], bfr[4];
#pragma unroll
      for (int mt = 0; mt < 4; ++mt) {
        int r = mt * 16 + lr;
        int cb = ((s << 6) | (kg << 4)) ^ ((r & 7) << 4);   // swizzled read
        af[mt] = *reinterpret_cast<const f16x8*>(abuf + r * 128 + cb);
      }
#pragma unroll
      for (int ct = 0; ct < 4; ++ct) {
        int c = col0 + ct * 16 + lr;
        bfr[ct] = *reinterpret_cast<const f16x8*>(Wt + (size_t)c * K + kk);
      }
#pragma unroll
      for (int mt = 0; mt < 4; ++mt)
#pragma unroll
        for (int ct = 0; ct < 4; ++ct)
          acc[mt][ct] = __builtin_amdgcn_mfma_f32_16x16x32_f16(af[mt], bfr[ct], acc[mt][ct], 0, 0, 0);
      if (wave == 0) {
        f16x8 eb = *reinterpret_cast<const f16x8*>(wart + lr * 256 + kk);
#pragma unroll
        for (int mt = 0; mt < 4; ++mt)
          acc_er[mt] = __builtin_amdgcn_mfma_f32_16x16x32_f16(af[mt], eb, acc_er[mt], 0, 0, 0);
      }
    }
    __syncthreads();
  }

  // C-write: col = lane&15, row = (lane>>4)*4 + reg
#pragma unroll
  for (int mt = 0; mt < 4; ++mt) {
#pragma unroll
    for (int r = 0; r < 4; ++r) {
      int row = row0 + mt * 16 + kg * 4 + r;
      if (row < M) {
#pragma unroll
        for (int ct = 0; ct < 4; ++ct) {
          int col = col0 + ct * 16 + lr;
          Z[(size_t)row * HF + col] = (_Float16)acc[mt][ct][r];
        }
      }
    }
  }
  // fused el epilogue: this wave's 64 cols == head(=wave)'s 64 dims
  float al4[4];
#pragma unroll
  for (int ct = 0; ct < 4; ++ct) al4[ct] = al[col0 + ct * 16 + lr];
#pragma unroll
  for (int mt = 0; mt < 4; ++mt) {
#pragma unroll
    for (int r = 0; r < 4; ++r) {
      float p = acc[mt][0][r] * al4[0] + acc[mt][1][r] * al4[1] +
                acc[mt][2][r] * al4[2] + acc[mt][3][r] * al4[3];
#pragma unroll
      for (int off = 1; off < 16; off <<= 1) p += __shfl_xor(p, off);
      int row = row0 + mt * 16 + kg * 4 + r;
      if (lr == 0 && row < M) EL[(size_t)row * 4 + wave] = p;
    }
  }
  // er epilogue (wave 0 only): er[row][h=lr<4]
  if (wave == 0 && lr < 4) {
#pragma unroll
    for (int mt = 0; mt < 4; ++mt) {
#pragma unroll
      for (int r = 0; r < 4; ++r) {
        int row = row0 + mt * 16 + kg * 4 + r;
        if (row < M) ER[(size_t)row * 4 + lr] = acc_er[mt][r];
      }
    }
  }
}

// ---------- CSR build (both relations per dispatch) ----------
__global__ __launch_bounds__(256) void k_hist2(const int* __restrict__ d0, const int* __restrict__ d1,
                                               int* __restrict__ c0, int* __restrict__ c1) {
  int t = blockIdx.x * 256 + threadIdx.x;
  if (t < NE) atomicAdd(&c0[d0[t]], 1);
  else if (t < 2 * NE) atomicAdd(&c1[d1[t - NE]], 1);
}

__global__ __launch_bounds__(1024) void k_scan1_2(const int* __restrict__ c0, const int* __restrict__ c1,
                                                  int* __restrict__ rp0, int* __restrict__ rp1,
                                                  int* __restrict__ b0, int* __restrict__ b1, int nscan) {
  __shared__ int tmp[1024];
  int rel = blockIdx.x >= nscan;
  int blk = rel ? blockIdx.x - nscan : blockIdx.x;
  const int* counts = rel ? c1 : c0;
  int* rp = rel ? rp1 : rp0;
  int* bsum = rel ? b1 : b0;
  int i = blk * 1024 + threadIdx.x;
  int v = (i < NN) ? counts[i] : 0;
  tmp[threadIdx.x] = v;
  __syncthreads();
  for (int off = 1; off < 1024; off <<= 1) {
    int t = (threadIdx.x >= off) ? tmp[threadIdx.x - off] : 0;
    __syncthreads();
    tmp[threadIdx.x] += t;
    __syncthreads();
  }
  if (i < NN) rp[i] = tmp[threadIdx.x] - v;  // block-local exclusive
  if (threadIdx.x == 1023) bsum[blk] = tmp[1023];
}

__global__ __launch_bounds__(128) void k_scan2_2(int* __restrict__ b0, int* __restrict__ b1, int nb) {
  int rel = threadIdx.x >> 6;
  int l = threadIdx.x & 63;
  int* bsum = rel ? b1 : b0;
  int orig = (l < nb) ? bsum[l] : 0;
  int v = orig;
#pragma unroll
  for (int off = 1; off < 64; off <<= 1) {
    int t = __shfl_up(v, off);
    if (l >= off) v += t;
  }
  if (l < nb) bsum[l] = v - orig;  // exclusive
}

__global__ __launch_bounds__(1024) void k_scan3_2(int* __restrict__ rp0, int* __restrict__ rp1,
                                                  const int* __restrict__ b0, const int* __restrict__ b1,
                                                  int nscan) {
  int rel = blockIdx.x >= nscan;
  int blk = rel ? blockIdx.x - nscan : blockIdx.x;
  int* rp = rel ? rp1 : rp0;
  const int* bsum = rel ? b1 : b0;
  int i = blk * 1024 + threadIdx.x;
  if (i < NN) rp[i] += bsum[blk];
  if (i == 0) rp[NN] = NE;
}

__global__ __launch_bounds__(256) void k_scatter2(
    const int* __restrict__ s0, const int* __restrict__ d0,
    const int* __restrict__ s1, const int* __restrict__ d1,
    const int* __restrict__ rp0, const int* __restrict__ rp1,
    int* __restrict__ f0, int* __restrict__ f1,
    int* __restrict__ cs0, int* __restrict__ cs1) {
  int t = blockIdx.x * 256 + threadIdx.x;
  if (t < NE) {
    int d = d0[t];
    int pos = rp0[d] + atomicAdd(&f0[d], 1);
    cs0[pos] = s0[t];
  } else if (t < 2 * NE) {
    int e = t - NE;
    int d = d1[e];
    int pos = rp1[d] + atomicAdd(&f1[d], 1);
    cs1[pos] = s1[e];
  }
}

// ---------- degree-sort permutation (64 buckets, both relations, LDS-privatized) ----------
__global__ __launch_bounds__(256) void k_deghist2(const int* __restrict__ rp0,
                                                  const int* __restrict__ rp1,
                                                  int* __restrict__ dh) {  // dh[2][64]
  __shared__ int h[128];
  if (threadIdx.x < 128) h[threadIdx.x] = 0;
  __syncthreads();
  int t = blockIdx.x * 256 + threadIdx.x;
  if (t < NN) {
    atomicAdd(&h[min(rp0[t + 1] - rp0[t], 63)], 1);
  } else if (t < 2 * NN) {
    int n = t - NN;
    atomicAdd(&h[64 + min(rp1[n + 1] - rp1[n], 63)], 1);
  }
  __syncthreads();
  if (threadIdx.x < 128) {
    int v = h[threadIdx.x];
    if (v) atomicAdd(&dh[threadIdx.x], v);
  }
}

__global__ __launch_bounds__(128) void k_degscan(const int* __restrict__ dh, int* __restrict__ dofs) {
  int rel = threadIdx.x >> 6;
  int l = threadIdx.x & 63;
  int orig = dh[rel * 64 + l];
  int v = orig;
#pragma unroll
  for (int off = 1; off < 64; off <<= 1) {
    int t = __shfl_up(v, off);
    if (l >= off) v += t;
  }
  dofs[rel * 64 + l] = v - orig;  // exclusive
}

__global__ __launch_bounds__(256) void k_permscatter2(const int* __restrict__ rp0,
                                                      const int* __restrict__ rp1,
                                                      const int* __restrict__ dofs,
                                                      int* __restrict__ dfill,
                                                      int* __restrict__ perm0,
                                                      int* __restrict__ perm1) {
  __shared__ int lcnt[128];
  __shared__ int lbase[128];
  if (threadIdx.x < 128) lcnt[threadIdx.x] = 0;
  __syncthreads();
  int t = blockIdx.x * 256 + threadIdx.x;
  int bucket = -1, node = 0, rank = 0, rel = 0;
  if (t < NN) {
    node = t; rel = 0;
    bucket = min(rp0[t + 1] - rp0[t], 63);
    rank = atomicAdd(&lcnt[bucket], 1);
  } else if (t < 2 * NN) {
    node = t - NN; rel = 1;
    bucket = 64 + min(rp1[node + 1] - rp1[node], 63);
    rank = atomicAdd(&lcnt[bucket], 1);
  }
  __syncthreads();
  if (threadIdx.x < 128) {
    int v = lcnt[threadIdx.x];
    lbase[threadIdx.x] = v ? atomicAdd(&dfill[threadIdx.x], v) : 0;
  }
  __syncthreads();
  if (bucket >= 0) {
    int pos = dofs[bucket] + lbase[bucket] + rank;
    if (rel == 0) perm0[pos] = node;
    else perm1[pos] = node;
  }
}

__device__ __forceinline__ float pick_h(float4 v, int h) {
  float r = v.x;
  r = (h == 1) ? v.y : r;
  r = (h == 2) ? v.z : r;
  r = (h == 3) ? v.w : r;
  return r;
}

// ---------- fused GAT aggregation v3: HALF-WAVE per dst node, degree-sorted ----------
// 32 lanes own a full node: lane owns 8 cols; no cross-half reduction needed.
template <typename OT>
__global__ __launch_bounds__(256) void k_agg3(
    const int* __restrict__ rpA, const int* __restrict__ csA, const int* __restrict__ permA,
    const float* __restrict__ elA, const float* __restrict__ erA,
    const _Float16* __restrict__ ZA, const float* __restrict__ bA, OT* __restrict__ oA,
    const int* __restrict__ rpB, const int* __restrict__ csB, const int* __restrict__ permB,
    const float* __restrict__ elB, const float* __restrict__ erB,
    const _Float16* __restrict__ ZB, const float* __restrict__ bB, OT* __restrict__ oB) {
  __shared__ float exs[8][128];
  __shared__ int ssrc[8][32];
  int nb = (NN + 7) / 8;
  int rel = blockIdx.x >= nb;
  int bid = rel ? blockIdx.x - nb : blockIdx.x;
  const int* rp = rel ? rpB : rpA;
  const int* csrc = rel ? csB : csA;
  const float* el = rel ? elB : elA;
  const float* er = rel ? erB : erA;
  const _Float16* Z = rel ? ZB : ZA;
  const float* bias = rel ? bB : bA;
  OT* out = rel ? oB : oA;

  int hidx = threadIdx.x >> 5;          // half index in block: 0..7
  int gid = bid * 8 + hidx;
  if (gid >= NN) return;
  int wid = (rel ? permB : permA)[gid];
  int l5 = threadIdx.x & 31;
  int c0 = l5 * 8;      // 8 cols per lane; 32 lanes cover all 256
  int h = l5 >> 3;      // head for cols c0..c0+7
  int beg = rp[wid], end = rp[wid + 1];
  int deg = end - beg;
  size_t obase = (size_t)wid * HF + c0;

  if (deg == 0) {
    float4 b0 = *reinterpret_cast<const float4*>(bias + c0);
    float4 b1 = *reinterpret_cast<const float4*>(bias + c0 + 4);
    if constexpr (std::is_same<OT, float>::value) {
      float4* op = reinterpret_cast<float4*>(out + obase);
      op[0] = b0; op[1] = b1;
    } else {
      f16x8 o = {(_Float16)b0.x, (_Float16)b0.y, (_Float16)b0.z, (_Float16)b0.w,
                 (_Float16)b1.x, (_Float16)b1.y, (_Float16)b1.z, (_Float16)b1.w};
      *reinterpret_cast<f16x8*>(out + obase) = o;
    }
    return;
  }

  float a8[8] = {0.f, 0.f, 0.f, 0.f, 0.f, 0.f, 0.f, 0.f};
  float inv;

  if (deg <= 32) {
    // ---- pass A: lane i (within half) owns edge i ----
    int s = 0;
    float4 x = {-1e30f, -1e30f, -1e30f, -1e30f};
    float4 b = *reinterpret_cast<const float4*>(er + (size_t)wid * 4);
    if (l5 < deg) {
      s = csrc[beg + l5];
      float4 a = reinterpret_cast<const float4*>(el)[s];
      x.x = a.x + b.x; x.x = x.x >= 0.f ? x.x : 0.2f * x.x;
      x.y = a.y + b.y; x.y = x.y >= 0.f ? x.y : 0.2f * x.y;
      x.z = a.z + b.z; x.z = x.z >= 0.f ? x.z : 0.2f * x.z;
      x.w = a.w + b.w; x.w = x.w >= 0.f ? x.w : 0.2f * x.w;
    }
    float4 m = x;
#pragma unroll
    for (int off = 16; off > 0; off >>= 1) {   // stays within the 32-lane half
      m.x = fmaxf(m.x, __shfl_xor(m.x, off));
      m.y = fmaxf(m.y, __shfl_xor(m.y, off));
      m.z = fmaxf(m.z, __shfl_xor(m.z, off));
      m.w = fmaxf(m.w, __shfl_xor(m.w, off));
    }
    float4 ex = {0.f, 0.f, 0.f, 0.f};
    if (l5 < deg) {
      ex.x = __expf(x.x - m.x);
      ex.y = __expf(x.y - m.y);
      ex.z = __expf(x.z - m.z);
      ex.w = __expf(x.w - m.w);
    }
    float4 sm = ex;
#pragma unroll
    for (int off = 16; off > 0; off >>= 1) {
      sm.x += __shfl_xor(sm.x, off);
      sm.y += __shfl_xor(sm.y, off);
      sm.z += __shfl_xor(sm.z, off);
      sm.w += __shfl_xor(sm.w, off);
    }
    inv = 1.0f / pick_h(sm, h);
    if (l5 < deg) {
      *reinterpret_cast<float4*>(&exs[hidx][l5 * 4]) = ex;
      ssrc[hidx][l5] = s;
    }
    // ---- pass B: half owns all its edges; fdot2 pairs, 2 pairs in flight ----
    int j = 0;
#define PAIR_STEP(J)                                                        \
    {                                                                       \
      int s1 = ssrc[hidx][(J)];                                             \
      int s2 = ssrc[hidx][(J) + 1];                                         \
      float w1 = exs[hidx][(J) * 4 + h];                                    \
      float w2 = exs[hidx][((J) + 1) * 4 + h];                              \
      f16x8 z1 = *reinterpret_cast<const f16x8*>(Z + (size_t)s1 * HF + c0); \
      f16x8 z2 = *reinterpret_cast<const f16x8*>(Z + (size_t)s2 * HF + c0); \
      f16x2 w12 = {(_Float16)w1, (_Float16)w2};                             \
      _Pragma("unroll")                                                     \
      for (int q = 0; q < 8; ++q) {                                         \
        f16x2 p = {z1[q], z2[q]};                                           \
        a8[q] = __builtin_amdgcn_fdot2(p, w12, a8[q], false);               \
      }                                                                     \
    }
    for (; j + 3 < deg; j += 4) { PAIR_STEP(j); PAIR_STEP(j + 2); }
    for (; j + 1 < deg; j += 2) { PAIR_STEP(j); }
#undef PAIR_STEP
    if (j < deg) {
      int sj = ssrc[hidx][j];
      float wj = exs[hidx][j * 4 + h];
      f16x8 z = *reinterpret_cast<const f16x8*>(Z + (size_t)sj * HF + c0);
#pragma unroll
      for (int q = 0; q < 8; ++q) a8[q] += wj * (float)z[q];
    }
  } else {
    // ---- rare fallback (deg > 32): serial two-pass over edges, half-wave ----
    float4 b = *reinterpret_cast<const float4*>(er + (size_t)wid * 4);
    float4 m = {-1e30f, -1e30f, -1e30f, -1e30f};
    for (int e = beg; e < end; ++e) {
      int s = csrc[e];
      float4 a = reinterpret_cast<const float4*>(el)[s];
      float4 x;
      x.x = a.x + b.x; x.x = x.x >= 0.f ? x.x : 0.2f * x.x;
      x.y = a.y + b.y; x.y = x.y >= 0.f ? x.y : 0.2f * x.y;
      x.z = a.z + b.z; x.z = x.z >= 0.f ? x.z : 0.2f * x.z;
      x.w = a.w + b.w; x.w = x.w >= 0.f ? x.w : 0.2f * x.w;
      m.x = fmaxf(m.x, x.x); m.y = fmaxf(m.y, x.y);
      m.z = fmaxf(m.z, x.z); m.w = fmaxf(m.w, x.w);
    }
    float4 sm = {0.f, 0.f, 0.f, 0.f};
    for (int e = beg; e < end; ++e) {
      int s = csrc[e];
      float4 a = reinterpret_cast<const float4*>(el)[s];
      float4 x;
      x.x = a.x + b.x; x.x = x.x >= 0.f ? x.x : 0.2f * x.x;
      x.y = a.y + b.y; x.y = x.y >= 0.f ? x.y : 0.2f * x.y;
      x.z = a.z + b.z; x.z = x.z >= 0.f ? x.z : 0.2f * x.z;
      x.w = a.w + b.w; x.w = x.w >= 0.f ? x.w : 0.2f * x.w;
      float4 exv;
      exv.x = __expf(x.x - m.x); exv.y = __expf(x.y - m.y);
      exv.z = __expf(x.z - m.z); exv.w = __expf(x.w - m.w);
      sm.x += exv.x; sm.y += exv.y; sm.z += exv.z; sm.w += exv.w;
      float w0 = pick_h(exv, h);
      f16x8 z = *reinterpret_cast<const f16x8*>(Z + (size_t)s * HF + c0);
#pragma unroll
      for (int q = 0; q < 8; ++q) a8[q] += w0 * (float)z[q];
    }
    inv = 1.0f / pick_h(sm, h);
  }

  float4 b0 = *reinterpret_cast<const float4*>(bias + c0);
  float4 b1 = *reinterpret_cast<const float4*>(bias + c0 + 4);
  float r0 = a8[0] * inv + b0.x, r1 = a8[1] * inv + b0.y;
  float r2 = a8[2] * inv + b0.z, r3 = a8[3] * inv + b0.w;
  float r4 = a8[4] * inv + b1.x, r5 = a8[5] * inv + b1.y;
  float r6 = a8[6] * inv + b1.z, r7 = a8[7] * inv + b1.w;
  if constexpr (std::is_same<OT, float>::value) {
    float4* op = reinterpret_cast<float4*>(out + obase);
    op[0] = (float4){r0, r1, r2, r3};
    op[1] = (float4){r4, r5, r6, r7};
  } else {
    f16x8 o = {(_Float16)r0, (_Float16)r1, (_Float16)r2, (_Float16)r3,
               (_Float16)r4, (_Float16)r5, (_Float16)r6, (_Float16)r7};
    *reinterpret_cast<f16x8*>(out + obase) = o;
  }
}

// ---------- batchnorm stats, both sides per dispatch ----------
__global__ __launch_bounds__(256) void k_bn_stats2(const _Float16* __restrict__ XU,
                                                   const _Float16* __restrict__ XI,
                                                   float* __restrict__ su, float* __restrict__ qu,
                                                   float* __restrict__ si, float* __restrict__ qi) {
  int rel = blockIdx.x >> 9;  // grid = 1024
  int blk = blockIdx.x & 511;
  const _Float16* X = rel ? XI : XU;
  float* sums = rel ? si : su;
  float* sqs = rel ? qi : qu;
  int c = threadIdx.x;
  float s = 0.f, q = 0.f;
  for (int r = blk; r < NN; r += 512) {
    float v = (float)X[(size_t)r * HF + c];
    s += v;
    q += v * v;
  }
  atomicAdd(&sums[c], s);
  atomicAdd(&sqs[c], q);
}

// ---------- batchnorm apply, both sides per dispatch (RAW16 -> H16) ----------
__global__ __launch_bounds__(256) void k_bn_apply2(
    const _Float16* __restrict__ XU, const _Float16* __restrict__ XI,
    const float* __restrict__ su, const float* __restrict__ qu,
    const float* __restrict__ si, const float* __restrict__ qi,
    const float* __restrict__ gU, const float* __restrict__ btU,
    const float* __restrict__ gI, const float* __restrict__ btI,
    _Float16* __restrict__ YU, _Float16* __restrict__ YI, int act) {
  const int nb = NN * HF / 8 / 256;  // 6250
  int rel = blockIdx.x >= nb;
  int bid = rel ? blockIdx.x - nb : blockIdx.x;
  const _Float16* X = rel ? XI : XU;
  const float* sums = rel ? si : su;
  const float* sqs = rel ? qi : qu;
  const float* g = rel ? gI : gU;
  const float* bt = rel ? btI : btU;
  _Float16* Y = rel ? YI : YU;
  int gid = bid * 256 + threadIdx.x;
  int i0 = gid * 8;
  int c0 = i0 & 255;
  const float invN = 1.0f / NN;
  f16x8 xv = *reinterpret_cast<const f16x8*>(X + i0);
  float4 s0 = *reinterpret_cast<const float4*>(sums + c0);
  float4 s1 = *reinterpret_cast<const float4*>(sums + c0 + 4);
  float4 q0 = *reinterpret_cast<const float4*>(sqs + c0);
  float4 q1 = *reinterpret_cast<const float4*>(sqs + c0 + 4);
  float4 g0 = *reinterpret_cast<const float4*>(g + c0);
  float4 g1 = *reinterpret_cast<const float4*>(g + c0 + 4);
  float4 b0 = *reinterpret_cast<const float4*>(bt + c0);
  float4 b1 = *reinterpret_cast<const float4*>(bt + c0 + 4);
  float sa[8] = {s0.x, s0.y, s0.z, s0.w, s1.x, s1.y, s1.z, s1.w};
  float qa[8] = {q0.x, q0.y, q0.z, q0.w, q1.x, q1.y, q1.z, q1.w};
  float ga[8] = {g0.x, g0.y, g0.z, g0.w, g1.x, g1.y, g1.z, g1.w};
  float ba[8] = {b0.x, b0.y, b0.z, b0.w, b1.x, b1.y, b1.z, b1.w};
  f16x8 o;
#pragma unroll
  for (int j = 0; j < 8; ++j) {
    float mu = sa[j] * invN;
    float var = qa[j] * invN - mu * mu;
    float sc = rsqrtf(var + 1e-5f) * ga[j];
    float v = ((float)xv[j] - mu) * sc + ba[j];
    v = act ? tanhf(v) : (v >= 0.f ? v : 0.01f * v);
    o[j] = (_Float16)v;
  }
  *reinterpret_cast<f16x8*>(Y + i0) = o;
}

extern "C" void kernel_launch(void* const* d_in, const int* in_sizes, int n_in,
                              void* d_out, int out_size, void* d_ws, size_t ws_size,
                              hipStream_t stream) {
  (void)in_sizes; (void)n_in; (void)out_size; (void)ws_size;
  const float* x_user = (const float*)d_in[0];
  const float* x_item = (const float*)d_in[1];
  const int* ui_src = (const int*)d_in[2];
  const int* ui_dst = (const int*)d_in[3];
  const int* iu_src = (const int*)d_in[4];
  const int* iu_dst = (const int*)d_in[5];
  const float *Wp[4], *alp[4], *arp[4], *bp[4];
  for (int l = 0; l < 4; ++l) {
    Wp[l]  = (const float*)d_in[6 + 4 * l];
    alp[l] = (const float*)d_in[7 + 4 * l];
    arp[l] = (const float*)d_in[8 + 4 * l];
    bp[l]  = (const float*)d_in[9 + 4 * l];
  }
  const float* bng = (const float*)d_in[22];
  const float* bnb = (const float*)d_in[23];

  char* w = (char*)d_ws;
  auto alloc = [&](size_t bytes) -> void* {
    void* p = (void*)w;
    w += (bytes + 255) & ~(size_t)255;
    return p;
  };
  _Float16* XU16 = (_Float16*)alloc((size_t)NN * 128 * 2);
  _Float16* XI16 = (_Float16*)alloc((size_t)NN * 128 * 2);
  _Float16* H16U = (_Float16*)alloc((size_t)NN * HF * 2);
  _Float16* H16I = (_Float16*)alloc((size_t)NN * HF * 2);
  _Float16* Z0 = (_Float16*)alloc((size_t)NN * HF * 2);
  _Float16* Z1 = (_Float16*)alloc((size_t)NN * HF * 2);
  _Float16* RAW16U = (_Float16*)alloc((size_t)NN * HF * 2);
  _Float16* RAW16I = (_Float16*)alloc((size_t)NN * HF * 2);
  float* EL0 = (float*)alloc((size_t)NN * 4 * 4);
  float* ER0 = (float*)alloc((size_t)NN * 4 * 4);
  float* EL1 = (float*)alloc((size_t)NN * 4 * 4);
  float* ER1 = (float*)alloc((size_t)NN * 4 * 4);
  _Float16* WT = (_Float16*)alloc((size_t)8 * 65536 * 2);
  _Float16* WART = (_Float16*)alloc((size_t)8 * 4096 * 2);  // [8][16][256] fp16
  int* rp_ui = (int*)alloc((size_t)(NN + 1) * 4);
  int* rp_iu = (int*)alloc((size_t)(NN + 1) * 4);
  int* csrc_ui = (int*)alloc((size_t)NE * 4);
  int* csrc_iu = (int*)alloc((size_t)NE * 4);
  int* perm_ui = (int*)alloc((size_t)NN * 4);
  int* perm_iu = (int*)alloc((size_t)NN * 4);
  int* counts = (int*)alloc((size_t)4 * NN * 4);  // counts_ui | counts_iu | fill_ui | fill_iu
  int* bsum_ui = (int*)alloc((size_t)64 * 4);
  int* bsum_iu = (int*)alloc((size_t)64 * 4);
  int* degws = (int*)alloc((size_t)384 * 4);      // dh[128] | dofs[128] | dfill[128]
  float* stats = (float*)alloc((size_t)6 * 512 * 4);

  int* counts_ui = counts;
  int* counts_iu = counts + NN;
  int* fill_ui = counts + 2 * NN;
  int* fill_iu = counts + 3 * NN;
  int* dh = degws;
  int* dofs = degws + 128;
  int* dfill = degws + 256;

  hipMemsetAsync(counts, 0, (size_t)4 * NN * 4, stream);
  hipMemsetAsync(stats, 0, (size_t)6 * 512 * 4, stream);
  hipMemsetAsync(WART, 0, (size_t)8 * 4096 * 2, stream);
  hipMemsetAsync(degws, 0, (size_t)384 * 4, stream);

  // input conversion (one dispatch)
  int n4 = NN * 128 / 4;
  k_tofp16_2<<<(2 * n4 + 255) / 256, 256, 0, stream>>>(x_user, x_item, XU16, XI16, n4);

  // all weight transposes (one dispatch)
  TArgs ta;
  int cum = 0;
  for (int l = 0; l < 4; ++l) {
    int K = (l == 0) ? 128 : 256;
    for (int r = 0; r < 2; ++r) {
      int s = l * 2 + r;
      ta.W[s] = Wp[l] + (size_t)r * K * HF;
      ta.dst[s] = WT + (size_t)s * 65536;
      ta.K[s] = K;
      ta.cum[s] = cum;
      cum += K * 256;
    }
  }
  ta.cum[8] = cum;
  k_transpose_all<<<(cum + 255) / 256, 256, 0, stream>>>(ta);

  // all W.ar attn tables, fp16 padded (one dispatch)
  k_makeattn_all<<<(8 * 256 * 4 + 255) / 256, 256, 0, stream>>>(
      Wp[0], Wp[1], Wp[2], Wp[3], arp[0], arp[1], arp[2], arp[3], WART);

  // CSR build (both relations per dispatch)
  int egrid2 = (2 * NE + 255) / 256;
  int nscan = (NN + 1023) / 1024;
  k_hist2<<<egrid2, 256, 0, stream>>>(ui_dst, iu_dst, counts_ui, counts_iu);
  k_scan1_2<<<2 * nscan, 1024, 0, stream>>>(counts_ui, counts_iu, rp_ui, rp_iu, bsum_ui, bsum_iu, nscan);
  k_scan2_2<<<1, 128, 0, stream>>>(bsum_ui, bsum_iu, nscan);
  k_scan3_2<<<2 * nscan, 1024, 0, stream>>>(rp_ui, rp_iu, bsum_ui, bsum_iu, nscan);
  k_scatter2<<<egrid2, 256, 0, stream>>>(ui_src, ui_dst, iu_src, iu_dst, rp_ui, rp_iu,
                                         fill_ui, fill_iu, csrc_ui, csrc_iu);

  // degree-sorted permutations (both relations, LDS-privatized atomics)
  int ngrid2 = (2 * NN + 255) / 256;
  k_deghist2<<<ngrid2, 256, 0, stream>>>(rp_ui, rp_iu, dh);
  k_degscan<<<1, 128, 0, stream>>>(dh, dofs);
  k_permscatter2<<<ngrid2, 256, 0, stream>>>(rp_ui, rp_iu, dofs, dfill, perm_ui, perm_iu);

  int agrid8 = (NN + 7) / 8;
  int nrow = (NN + 63) / 64;
  float* out_user = (float*)d_out;
  float* out_item = (float*)d_out + (size_t)NN * HF;

  for (int l = 0; l < 4; ++l) {
    int K = (l == 0) ? 128 : 256;
    const _Float16* Au = (l == 0) ? XU16 : H16U;
    const _Float16* Ai = (l == 0) ? XI16 : H16I;

    // GEMM pair: Z0 = hu@W0 (+el0, +er1), Z1 = hi@W1 (+el1, +er0)
    GArgs ga;
    ga.A0 = Au; ga.A1 = Ai;
    ga.Wt0 = WT + (size_t)(l * 2 + 0) * 65536;
    ga.Wt1 = WT + (size_t)(l * 2 + 1) * 65536;
    ga.Z0 = Z0; ga.Z1 = Z1;
    ga.al0 = alp[l] + 0; ga.al1 = alp[l] + 256;
    ga.EL0 = EL0; ga.EL1 = EL1;
    ga.wart_s0 = WART + (size_t)(l * 2 + 1) * 4096;  // side0 (A=hu) -> er1 = hu.(W1.ar1)
    ga.wart_s1 = WART + (size_t)(l * 2 + 0) * 4096;  // side1 (A=hi) -> er0 = hi.(W0.ar0)
    ga.ER_s0 = ER1; ga.ER_s1 = ER0;
    ga.M = NN; ga.K = K;
    k_gemm5<<<2 * nrow, 256, 0, stream>>>(ga);

    // aggregation pair: u->i (dst items, Z0) and i->u (dst users, Z1)
    if (l < 3)
      k_agg3<_Float16><<<2 * agrid8, 256, 0, stream>>>(
          rp_ui, csrc_ui, perm_ui, EL0, ER0, Z0, bp[l] + 0, RAW16I,
          rp_iu, csrc_iu, perm_iu, EL1, ER1, Z1, bp[l] + 256, RAW16U);
    else
      k_agg3<float><<<2 * agrid8, 256, 0, stream>>>(
          rp_ui, csrc_ui, perm_ui, EL0, ER0, Z0, bp[l] + 0, out_item,
          rp_iu, csrc_iu, perm_iu, EL1, ER1, Z1, bp[l] + 256, out_user);

    if (l < 3) {
      int act = (l == 2) ? 1 : 0;
      float* su = stats + (size_t)(l * 2 + 0) * 512;
      float* si = stats + (size_t)(l * 2 + 1) * 512;
      k_bn_stats2<<<1024, 256, 0, stream>>>(RAW16U, RAW16I, su, su + 256, si, si + 256);
      k_bn_apply2<<<2 * (NN * HF / 8 / 256), 256, 0, stream>>>(
          RAW16U, RAW16I, su, su + 256, si, si + 256,
          bng + (size_t)(l * 2 + 0) * 256, bnb + (size_t)(l * 2 + 0) * 256,
          bng + (size_t)(l * 2 + 1) * 256, bnb + (size_t)(l * 2 + 1) * 256,
          H16U, H16I, act);
    }
  }
}

// Round 16
// 943.040 us; speedup vs baseline: 1.4202x; 1.0109x over previous
//
#include <hip/hip_runtime.h>
#include <hip/hip_bf16.h>
#include <type_traits>

#define NN 50000     // nodes per side (users == items == 50000)
#define NE 600000    // edges per relation
#define HF 256       // hidden features

typedef float f32x4 __attribute__((ext_vector_type(4)));
typedef _Float16 f16x8 __attribute__((ext_vector_type(8)));
typedef _Float16 f16x4 __attribute__((ext_vector_type(4)));
typedef _Float16 f16x2 __attribute__((ext_vector_type(2)));

// ---------- fp32 -> fp16 convert, both inputs in one dispatch ----------
__global__ __launch_bounds__(256) void k_tofp16_2(const float* __restrict__ A,
                                                  const float* __restrict__ B,
                                                  _Float16* __restrict__ OA,
                                                  _Float16* __restrict__ OB, int n4) {
  int i = blockIdx.x * 256 + threadIdx.x;
  const float* X = (i < n4) ? A : B;
  _Float16* Y = (i < n4) ? OA : OB;
  int j = (i < n4) ? i : i - n4;
  if (j < n4) {
    float4 v = reinterpret_cast<const float4*>(X)[j];
    f16x4 o = {(_Float16)v.x, (_Float16)v.y, (_Float16)v.z, (_Float16)v.w};
    reinterpret_cast<f16x4*>(Y)[j] = o;
  }
}

// ---------- all 8 W[K][256] -> Wt[256][K] transposes in one dispatch ----------
struct TArgs {
  const float* W[8];
  _Float16* dst[8];
  int K[8];
  int cum[9];
};
__global__ __launch_bounds__(256) void k_transpose_all(TArgs t) {
  int idx = blockIdx.x * 256 + threadIdx.x;
#pragma unroll
  for (int s = 0; s < 8; ++s) {
    if (idx >= t.cum[s] && idx < t.cum[s + 1]) {
      int local = idx - t.cum[s];
      int K = t.K[s];
      int k = local >> 8;
      int n = local & 255;
      t.dst[s][(size_t)n * K + k] = (_Float16)t.W[s][local];
    }
  }
}

// ---------- all W.ar attn tables, fp16 [16][256]-padded, in one dispatch ----------
__global__ __launch_bounds__(256) void k_makeattn_all(
    const float* __restrict__ W1, const float* __restrict__ W2,
    const float* __restrict__ W3, const float* __restrict__ W4,
    const float* __restrict__ ar1, const float* __restrict__ ar2,
    const float* __restrict__ ar3, const float* __restrict__ ar4,
    _Float16* __restrict__ wart) {   // [8][16][256] fp16, cols 4..15 stay zero
  int idx = blockIdx.x * 256 + threadIdx.x;
  if (idx >= 8 * 256 * 4) return;
  int h = idx & 3;
  int k = (idx >> 2) & 255;
  int s = idx >> 10;  // l*2+r
  int l = s >> 1, r = s & 1;
  int K = (l == 0) ? 128 : 256;
  if (k >= K) return;
  const float* W = (l == 0 ? W1 : l == 1 ? W2 : l == 2 ? W3 : W4) + (size_t)r * K * 256;
  const float* a = (l == 0 ? ar1 : l == 1 ? ar2 : l == 2 ? ar3 : ar4) + r * 256 + h * 64;
  const float* wrow = W + (size_t)k * 256 + h * 64;
  float sum = 0.f;
#pragma unroll 8
  for (int d = 0; d < 64; ++d) sum += wrow[d] * a[d];
  wart[(size_t)s * 4096 + h * 256 + k] = (_Float16)sum;
}

// ---------- GEMM v6: 64x256 tile, BK=128, LDS-staged A (swizzled) dbuf, fused el + er(MFMA) ----------
struct GArgs {
  const _Float16* A0; const _Float16* A1;     // post-BN activations
  const _Float16* Wt0; const _Float16* Wt1;
  _Float16* Z0; _Float16* Z1;
  const float* al0; const float* al1;
  float* EL0; float* EL1;
  const _Float16* wart_s0; const _Float16* wart_s1;  // [16][256] fp16 W.ar tables
  float* ER_s0; float* ER_s1;                 // side0 -> ER1, side1 -> ER0
  int M, K;
};

__global__ __launch_bounds__(256) void k_gemm5(GArgs ga) {
  __shared__ _Float16 As[2][64 * 128];   // 2 x 16 KB double buffer, BK=128
  const int nrow = (NN + 63) / 64;       // 782
  int side = blockIdx.x >= nrow;
  int bid = side ? blockIdx.x - nrow : blockIdx.x;
  const _Float16* A = side ? ga.A1 : ga.A0;
  const _Float16* Wt = side ? ga.Wt1 : ga.Wt0;
  _Float16* Z = side ? ga.Z1 : ga.Z0;
  const float* al = side ? ga.al1 : ga.al0;
  float* EL = side ? ga.EL1 : ga.EL0;
  const _Float16* wart = side ? ga.wart_s1 : ga.wart_s0;
  float* ER = side ? ga.ER_s1 : ga.ER_s0;
  const int K = ga.K, M = ga.M;
  int row0 = bid * 64;
  int wave = threadIdx.x >> 6;           // wave == head; cols wave*64..
  int lane = threadIdx.x & 63;
  int lr = lane & 15, kg = lane >> 4;
  int col0 = wave * 64;

  // stage A tile [row0..row0+64) x [k0..k0+128) into As[buf]; source pre-swizzled
  auto stage = [&](int buf, int k0) {
#pragma unroll
    for (int j = 0; j < 4; ++j) {
      int Lb = j * 4096 + wave * 1024;          // wave-uniform LDS byte base
      int L = Lb + lane * 16;                   // this lane's linear slot
      int r = L >> 8;                           // row in tile (256B per row)
      int kb = (L & 255) ^ ((r & 7) << 4);      // pre-swizzled source column byte
      int rg = row0 + r; rg = rg < M ? rg : M - 1;
      const char* gsrc = (const char*)A + ((size_t)rg * K + k0) * 2 + kb;
      char* ldst = (char*)(&As[buf][0]) + Lb;
      __builtin_amdgcn_global_load_lds(
          (const __attribute__((address_space(1))) unsigned int*)gsrc,
          (__attribute__((address_space(3))) unsigned int*)ldst, 16, 0, 0);
    }
  };

  f32x4 acc[4][4];
#pragma unroll
  for (int i = 0; i < 4; ++i)
#pragma unroll
    for (int j = 0; j < 4; ++j) acc[i][j] = (f32x4){0.f, 0.f, 0.f, 0.f};
  f32x4 acc_er[4];
#pragma unroll
  for (int i = 0; i < 4; ++i) acc_er[i] = (f32x4){0.f, 0.f, 0.f, 0.f};

  int nt = K >> 7;   // BK = 128 (K is 128 or 256)
  stage(0, 0);
  __syncthreads();
  for (int t = 0; t < nt; ++t) {
    if (t + 1 < nt) stage((t + 1) & 1, (t + 1) * 128);
    const char* abuf = (const char*)(&As[t & 1][0]);
#pragma unroll
    for (int s = 0; s < 4; ++s) {
      int kk = t * 128 + s * 32 + kg * 8;
      f16x8 af[4], bfr[4];
#pragma unroll
      for (int mt = 0; mt < 4; ++mt) {
        int r = mt * 16 + lr;
        int cb = ((s << 6) | (kg << 4)) ^ ((r & 7) << 4);   // swizzled read (byte in 256B row)
        af[mt] = *reinterpret_cast<const f16x8*>(abuf + r * 256 + cb);
      }
#pragma unroll
      for (int ct = 0; ct < 4; ++ct) {
        int c = col0 + ct * 16 + lr;
        bfr[ct] = *reinterpret_cast<const f16x8*>(Wt + (size_t)c * K + kk);
      }
#pragma unroll
      for (int mt = 0; mt < 4; ++mt)
#pragma unroll
        for (int ct = 0; ct < 4; ++ct)
          acc[mt][ct] = __builtin_amdgcn_mfma_f32_16x16x32_f16(af[mt], bfr[ct], acc[mt][ct], 0, 0, 0);
      if (wave == 0) {
        f16x8 eb = *reinterpret_cast<const f16x8*>(wart + lr * 256 + kk);
#pragma unroll
        for (int mt = 0; mt < 4; ++mt)
          acc_er[mt] = __builtin_amdgcn_mfma_f32_16x16x32_f16(af[mt], eb, acc_er[mt], 0, 0, 0);
      }
    }
    if (t + 1 < nt) __syncthreads();
  }

  // C-write: col = lane&15, row = (lane>>4)*4 + reg
#pragma unroll
  for (int mt = 0; mt < 4; ++mt) {
#pragma unroll
    for (int r = 0; r < 4; ++r) {
      int row = row0 + mt * 16 + kg * 4 + r;
      if (row < M) {
#pragma unroll
        for (int ct = 0; ct < 4; ++ct) {
          int col = col0 + ct * 16 + lr;
          Z[(size_t)row * HF + col] = (_Float16)acc[mt][ct][r];
        }
      }
    }
  }
  // fused el epilogue: this wave's 64 cols == head(=wave)'s 64 dims
  float al4[4];
#pragma unroll
  for (int ct = 0; ct < 4; ++ct) al4[ct] = al[col0 + ct * 16 + lr];
#pragma unroll
  for (int mt = 0; mt < 4; ++mt) {
#pragma unroll
    for (int r = 0; r < 4; ++r) {
      float p = acc[mt][0][r] * al4[0] + acc[mt][1][r] * al4[1] +
                acc[mt][2][r] * al4[2] + acc[mt][3][r] * al4[3];
#pragma unroll
      for (int off = 1; off < 16; off <<= 1) p += __shfl_xor(p, off);
      int row = row0 + mt * 16 + kg * 4 + r;
      if (lr == 0 && row < M) EL[(size_t)row * 4 + wave] = p;
    }
  }
  // er epilogue (wave 0 only): er[row][h=lr<4]
  if (wave == 0 && lr < 4) {
#pragma unroll
    for (int mt = 0; mt < 4; ++mt) {
#pragma unroll
      for (int r = 0; r < 4; ++r) {
        int row = row0 + mt * 16 + kg * 4 + r;
        if (row < M) ER[(size_t)row * 4 + lr] = acc_er[mt][r];
      }
    }
  }
}

// ---------- CSR build (both relations per dispatch) ----------
__global__ __launch_bounds__(256) void k_hist2(const int* __restrict__ d0, const int* __restrict__ d1,
                                               int* __restrict__ c0, int* __restrict__ c1) {
  int t = blockIdx.x * 256 + threadIdx.x;
  if (t < NE) atomicAdd(&c0[d0[t]], 1);
  else if (t < 2 * NE) atomicAdd(&c1[d1[t - NE]], 1);
}

__global__ __launch_bounds__(1024) void k_scan1_2(const int* __restrict__ c0, const int* __restrict__ c1,
                                                  int* __restrict__ rp0, int* __restrict__ rp1,
                                                  int* __restrict__ b0, int* __restrict__ b1, int nscan) {
  __shared__ int tmp[1024];
  int rel = blockIdx.x >= nscan;
  int blk = rel ? blockIdx.x - nscan : blockIdx.x;
  const int* counts = rel ? c1 : c0;
  int* rp = rel ? rp1 : rp0;
  int* bsum = rel ? b1 : b0;
  int i = blk * 1024 + threadIdx.x;
  int v = (i < NN) ? counts[i] : 0;
  tmp[threadIdx.x] = v;
  __syncthreads();
  for (int off = 1; off < 1024; off <<= 1) {
    int t = (threadIdx.x >= off) ? tmp[threadIdx.x - off] : 0;
    __syncthreads();
    tmp[threadIdx.x] += t;
    __syncthreads();
  }
  if (i < NN) rp[i] = tmp[threadIdx.x] - v;  // block-local exclusive
  if (threadIdx.x == 1023) bsum[blk] = tmp[1023];
}

__global__ __launch_bounds__(128) void k_scan2_2(int* __restrict__ b0, int* __restrict__ b1, int nb) {
  int rel = threadIdx.x >> 6;
  int l = threadIdx.x & 63;
  int* bsum = rel ? b1 : b0;
  int orig = (l < nb) ? bsum[l] : 0;
  int v = orig;
#pragma unroll
  for (int off = 1; off < 64; off <<= 1) {
    int t = __shfl_up(v, off);
    if (l >= off) v += t;
  }
  if (l < nb) bsum[l] = v - orig;  // exclusive
}

__global__ __launch_bounds__(1024) void k_scan3_2(int* __restrict__ rp0, int* __restrict__ rp1,
                                                  const int* __restrict__ b0, const int* __restrict__ b1,
                                                  int nscan) {
  int rel = blockIdx.x >= nscan;
  int blk = rel ? blockIdx.x - nscan : blockIdx.x;
  int* rp = rel ? rp1 : rp0;
  const int* bsum = rel ? b1 : b0;
  int i = blk * 1024 + threadIdx.x;
  if (i < NN) rp[i] += bsum[blk];
  if (i == 0) rp[NN] = NE;
}

__global__ __launch_bounds__(256) void k_scatter2(
    const int* __restrict__ s0, const int* __restrict__ d0,
    const int* __restrict__ s1, const int* __restrict__ d1,
    const int* __restrict__ rp0, const int* __restrict__ rp1,
    int* __restrict__ f0, int* __restrict__ f1,
    int* __restrict__ cs0, int* __restrict__ cs1) {
  int t = blockIdx.x * 256 + threadIdx.x;
  if (t < NE) {
    int d = d0[t];
    int pos = rp0[d] + atomicAdd(&f0[d], 1);
    cs0[pos] = s0[t];
  } else if (t < 2 * NE) {
    int e = t - NE;
    int d = d1[e];
    int pos = rp1[d] + atomicAdd(&f1[d], 1);
    cs1[pos] = s1[e];
  }
}

// ---------- degree-sort permutation (64 buckets, both relations, LDS-privatized) ----------
__global__ __launch_bounds__(256) void k_deghist2(const int* __restrict__ rp0,
                                                  const int* __restrict__ rp1,
                                                  int* __restrict__ dh) {  // dh[2][64]
  __shared__ int h[128];
  if (threadIdx.x < 128) h[threadIdx.x] = 0;
  __syncthreads();
  int t = blockIdx.x * 256 + threadIdx.x;
  if (t < NN) {
    atomicAdd(&h[min(rp0[t + 1] - rp0[t], 63)], 1);
  } else if (t < 2 * NN) {
    int n = t - NN;
    atomicAdd(&h[64 + min(rp1[n + 1] - rp1[n], 63)], 1);
  }
  __syncthreads();
  if (threadIdx.x < 128) {
    int v = h[threadIdx.x];
    if (v) atomicAdd(&dh[threadIdx.x], v);
  }
}

__global__ __launch_bounds__(128) void k_degscan(const int* __restrict__ dh, int* __restrict__ dofs) {
  int rel = threadIdx.x >> 6;
  int l = threadIdx.x & 63;
  int orig = dh[rel * 64 + l];
  int v = orig;
#pragma unroll
  for (int off = 1; off < 64; off <<= 1) {
    int t = __shfl_up(v, off);
    if (l >= off) v += t;
  }
  dofs[rel * 64 + l] = v - orig;  // exclusive
}

__global__ __launch_bounds__(256) void k_permscatter2(const int* __restrict__ rp0,
                                                      const int* __restrict__ rp1,
                                                      const int* __restrict__ dofs,
                                                      int* __restrict__ dfill,
                                                      int* __restrict__ perm0,
                                                      int* __restrict__ perm1) {
  __shared__ int lcnt[128];
  __shared__ int lbase[128];
  if (threadIdx.x < 128) lcnt[threadIdx.x] = 0;
  __syncthreads();
  int t = blockIdx.x * 256 + threadIdx.x;
  int bucket = -1, node = 0, rank = 0, rel = 0;
  if (t < NN) {
    node = t; rel = 0;
    bucket = min(rp0[t + 1] - rp0[t], 63);
    rank = atomicAdd(&lcnt[bucket], 1);
  } else if (t < 2 * NN) {
    node = t - NN; rel = 1;
    bucket = 64 + min(rp1[node + 1] - rp1[node], 63);
    rank = atomicAdd(&lcnt[bucket], 1);
  }
  __syncthreads();
  if (threadIdx.x < 128) {
    int v = lcnt[threadIdx.x];
    lbase[threadIdx.x] = v ? atomicAdd(&dfill[threadIdx.x], v) : 0;
  }
  __syncthreads();
  if (bucket >= 0) {
    int pos = dofs[bucket] + lbase[bucket] + rank;
    if (rel == 0) perm0[pos] = node;
    else perm1[pos] = node;
  }
}

__device__ __forceinline__ float pick_h(float4 v, int h) {
  float r = v.x;
  r = (h == 1) ? v.y : r;
  r = (h == 2) ? v.z : r;
  r = (h == 3) ? v.w : r;
  return r;
}

// ---------- fused GAT aggregation v3: HALF-WAVE per dst node, degree-sorted ----------
template <typename OT>
__global__ __launch_bounds__(256) void k_agg3(
    const int* __restrict__ rpA, const int* __restrict__ csA, const int* __restrict__ permA,
    const float* __restrict__ elA, const float* __restrict__ erA,
    const _Float16* __restrict__ ZA, const float* __restrict__ bA, OT* __restrict__ oA,
    const int* __restrict__ rpB, const int* __restrict__ csB, const int* __restrict__ permB,
    const float* __restrict__ elB, const float* __restrict__ erB,
    const _Float16* __restrict__ ZB, const float* __restrict__ bB, OT* __restrict__ oB) {
  __shared__ float exs[8][128];
  __shared__ int ssrc[8][32];
  int nb = (NN + 7) / 8;
  int rel = blockIdx.x >= nb;
  int bid = rel ? blockIdx.x - nb : blockIdx.x;
  const int* rp = rel ? rpB : rpA;
  const int* csrc = rel ? csB : csA;
  const float* el = rel ? elB : elA;
  const float* er = rel ? erB : erA;
  const _Float16* Z = rel ? ZB : ZA;
  const float* bias = rel ? bB : bA;
  OT* out = rel ? oB : oA;

  int hidx = threadIdx.x >> 5;          // half index in block: 0..7
  int gid = bid * 8 + hidx;
  if (gid >= NN) return;
  int wid = (rel ? permB : permA)[gid];
  int l5 = threadIdx.x & 31;
  int c0 = l5 * 8;      // 8 cols per lane; 32 lanes cover all 256
  int h = l5 >> 3;      // head for cols c0..c0+7
  int beg = rp[wid], end = rp[wid + 1];
  int deg = end - beg;
  size_t obase = (size_t)wid * HF + c0;

  if (deg == 0) {
    float4 b0 = *reinterpret_cast<const float4*>(bias + c0);
    float4 b1 = *reinterpret_cast<const float4*>(bias + c0 + 4);
    if constexpr (std::is_same<OT, float>::value) {
      float4* op = reinterpret_cast<float4*>(out + obase);
      op[0] = b0; op[1] = b1;
    } else {
      f16x8 o = {(_Float16)b0.x, (_Float16)b0.y, (_Float16)b0.z, (_Float16)b0.w,
                 (_Float16)b1.x, (_Float16)b1.y, (_Float16)b1.z, (_Float16)b1.w};
      *reinterpret_cast<f16x8*>(out + obase) = o;
    }
    return;
  }

  float a8[8] = {0.f, 0.f, 0.f, 0.f, 0.f, 0.f, 0.f, 0.f};
  float inv;

  if (deg <= 32) {
    // ---- pass A: lane i (within half) owns edge i ----
    int s = 0;
    float4 x = {-1e30f, -1e30f, -1e30f, -1e30f};
    float4 b = *reinterpret_cast<const float4*>(er + (size_t)wid * 4);
    if (l5 < deg) {
      s = csrc[beg + l5];
      float4 a = reinterpret_cast<const float4*>(el)[s];
      x.x = a.x + b.x; x.x = x.x >= 0.f ? x.x : 0.2f * x.x;
      x.y = a.y + b.y; x.y = x.y >= 0.f ? x.y : 0.2f * x.y;
      x.z = a.z + b.z; x.z = x.z >= 0.f ? x.z : 0.2f * x.z;
      x.w = a.w + b.w; x.w = x.w >= 0.f ? x.w : 0.2f * x.w;
    }
    float4 m = x;
#pragma unroll
    for (int off = 16; off > 0; off >>= 1) {   // stays within the 32-lane half
      m.x = fmaxf(m.x, __shfl_xor(m.x, off));
      m.y = fmaxf(m.y, __shfl_xor(m.y, off));
      m.z = fmaxf(m.z, __shfl_xor(m.z, off));
      m.w = fmaxf(m.w, __shfl_xor(m.w, off));
    }
    float4 ex = {0.f, 0.f, 0.f, 0.f};
    if (l5 < deg) {
      ex.x = __expf(x.x - m.x);
      ex.y = __expf(x.y - m.y);
      ex.z = __expf(x.z - m.z);
      ex.w = __expf(x.w - m.w);
    }
    float4 sm = ex;
#pragma unroll
    for (int off = 16; off > 0; off >>= 1) {
      sm.x += __shfl_xor(sm.x, off);
      sm.y += __shfl_xor(sm.y, off);
      sm.z += __shfl_xor(sm.z, off);
      sm.w += __shfl_xor(sm.w, off);
    }
    inv = 1.0f / pick_h(sm, h);
    if (l5 < deg) {
      *reinterpret_cast<float4*>(&exs[hidx][l5 * 4]) = ex;
      ssrc[hidx][l5] = s;
    }
    // ---- pass B: half owns all its edges; fdot2 pairs, 2 pairs in flight ----
    int j = 0;
#define PAIR_STEP(J)                                                        \
    {                                                                       \
      int s1 = ssrc[hidx][(J)];                                             \
      int s2 = ssrc[hidx][(J) + 1];                                         \
      float w1 = exs[hidx][(J) * 4 + h];                                    \
      float w2 = exs[hidx][((J) + 1) * 4 + h];                              \
      f16x8 z1 = *reinterpret_cast<const f16x8*>(Z + (size_t)s1 * HF + c0); \
      f16x8 z2 = *reinterpret_cast<const f16x8*>(Z + (size_t)s2 * HF + c0); \
      f16x2 w12 = {(_Float16)w1, (_Float16)w2};                             \
      _Pragma("unroll")                                                     \
      for (int q = 0; q < 8; ++q) {                                         \
        f16x2 p = {z1[q], z2[q]};                                           \
        a8[q] = __builtin_amdgcn_fdot2(p, w12, a8[q], false);               \
      }                                                                     \
    }
    for (; j + 3 < deg; j += 4) { PAIR_STEP(j); PAIR_STEP(j + 2); }
    for (; j + 1 < deg; j += 2) { PAIR_STEP(j); }
#undef PAIR_STEP
    if (j < deg) {
      int sj = ssrc[hidx][j];
      float wj = exs[hidx][j * 4 + h];
      f16x8 z = *reinterpret_cast<const f16x8*>(Z + (size_t)sj * HF + c0);
#pragma unroll
      for (int q = 0; q < 8; ++q) a8[q] += wj * (float)z[q];
    }
  } else {
    // ---- rare fallback (deg > 32): serial two-pass over edges, half-wave ----
    float4 b = *reinterpret_cast<const float4*>(er + (size_t)wid * 4);
    float4 m = {-1e30f, -1e30f, -1e30f, -1e30f};
    for (int e = beg; e < end; ++e) {
      int s = csrc[e];
      float4 a = reinterpret_cast<const float4*>(el)[s];
      float4 x;
      x.x = a.x + b.x; x.x = x.x >= 0.f ? x.x : 0.2f * x.x;
      x.y = a.y + b.y; x.y = x.y >= 0.f ? x.y : 0.2f * x.y;
      x.z = a.z + b.z; x.z = x.z >= 0.f ? x.z : 0.2f * x.z;
      x.w = a.w + b.w; x.w = x.w >= 0.f ? x.w : 0.2f * x.w;
      m.x = fmaxf(m.x, x.x); m.y = fmaxf(m.y, x.y);
      m.z = fmaxf(m.z, x.z); m.w = fmaxf(m.w, x.w);
    }
    float4 sm = {0.f, 0.f, 0.f, 0.f};
    for (int e = beg; e < end; ++e) {
      int s = csrc[e];
      float4 a = reinterpret_cast<const float4*>(el)[s];
      float4 x;
      x.x = a.x + b.x; x.x = x.x >= 0.f ? x.x : 0.2f * x.x;
      x.y = a.y + b.y; x.y = x.y >= 0.f ? x.y : 0.2f * x.y;
      x.z = a.z + b.z; x.z = x.z >= 0.f ? x.z : 0.2f * x.z;
      x.w = a.w + b.w; x.w = x.w >= 0.f ? x.w : 0.2f * x.w;
      float4 exv;
      exv.x = __expf(x.x - m.x); exv.y = __expf(x.y - m.y);
      exv.z = __expf(x.z - m.z); exv.w = __expf(x.w - m.w);
      sm.x += exv.x; sm.y += exv.y; sm.z += exv.z; sm.w += exv.w;
      float w0 = pick_h(exv, h);
      f16x8 z = *reinterpret_cast<const f16x8*>(Z + (size_t)s * HF + c0);
#pragma unroll
      for (int q = 0; q < 8; ++q) a8[q] += w0 * (float)z[q];
    }
    inv = 1.0f / pick_h(sm, h);
  }

  float4 b0 = *reinterpret_cast<const float4*>(bias + c0);
  float4 b1 = *reinterpret_cast<const float4*>(bias + c0 + 4);
  float r0 = a8[0] * inv + b0.x, r1 = a8[1] * inv + b0.y;
  float r2 = a8[2] * inv + b0.z, r3 = a8[3] * inv + b0.w;
  float r4 = a8[4] * inv + b1.x, r5 = a8[5] * inv + b1.y;
  float r6 = a8[6] * inv + b1.z, r7 = a8[7] * inv + b1.w;
  if constexpr (std::is_same<OT, float>::value) {
    float4* op = reinterpret_cast<float4*>(out + obase);
    op[0] = (float4){r0, r1, r2, r3};
    op[1] = (float4){r4, r5, r6, r7};
  } else {
    f16x8 o = {(_Float16)r0, (_Float16)r1, (_Float16)r2, (_Float16)r3,
               (_Float16)r4, (_Float16)r5, (_Float16)r6, (_Float16)r7};
    *reinterpret_cast<f16x8*>(out + obase) = o;
  }
}

// ---------- batchnorm stats, both sides per dispatch ----------
__global__ __launch_bounds__(256) void k_bn_stats2(const _Float16* __restrict__ XU,
                                                   const _Float16* __restrict__ XI,
                                                   float* __restrict__ su, float* __restrict__ qu,
                                                   float* __restrict__ si, float* __restrict__ qi) {
  int rel = blockIdx.x >> 9;  // grid = 1024
  int blk = blockIdx.x & 511;
  const _Float16* X = rel ? XI : XU;
  float* sums = rel ? si : su;
  float* sqs = rel ? qi : qu;
  int c = threadIdx.x;
  float s = 0.f, q = 0.f;
  for (int r = blk; r < NN; r += 512) {
    float v = (float)X[(size_t)r * HF + c];
    s += v;
    q += v * v;
  }
  atomicAdd(&sums[c], s);
  atomicAdd(&sqs[c], q);
}

// ---------- batchnorm apply, both sides per dispatch (RAW16 -> H16) ----------
__global__ __launch_bounds__(256) void k_bn_apply2(
    const _Float16* __restrict__ XU, const _Float16* __restrict__ XI,
    const float* __restrict__ su, const float* __restrict__ qu,
    const float* __restrict__ si, const float* __restrict__ qi,
    const float* __restrict__ gU, const float* __restrict__ btU,
    const float* __restrict__ gI, const float* __restrict__ btI,
    _Float16* __restrict__ YU, _Float16* __restrict__ YI, int act) {
  const int nb = NN * HF / 8 / 256;  // 6250
  int rel = blockIdx.x >= nb;
  int bid = rel ? blockIdx.x - nb : blockIdx.x;
  const _Float16* X = rel ? XI : XU;
  const float* sums = rel ? si : su;
  const float* sqs = rel ? qi : qu;
  const float* g = rel ? gI : gU;
  const float* bt = rel ? btI : btU;
  _Float16* Y = rel ? YI : YU;
  int gid = bid * 256 + threadIdx.x;
  int i0 = gid * 8;
  int c0 = i0 & 255;
  const float invN = 1.0f / NN;
  f16x8 xv = *reinterpret_cast<const f16x8*>(X + i0);
  float4 s0 = *reinterpret_cast<const float4*>(sums + c0);
  float4 s1 = *reinterpret_cast<const float4*>(sums + c0 + 4);
  float4 q0 = *reinterpret_cast<const float4*>(sqs + c0);
  float4 q1 = *reinterpret_cast<const float4*>(sqs + c0 + 4);
  float4 g0 = *reinterpret_cast<const float4*>(g + c0);
  float4 g1 = *reinterpret_cast<const float4*>(g + c0 + 4);
  float4 b0 = *reinterpret_cast<const float4*>(bt + c0);
  float4 b1 = *reinterpret_cast<const float4*>(bt + c0 + 4);
  float sa[8] = {s0.x, s0.y, s0.z, s0.w, s1.x, s1.y, s1.z, s1.w};
  float qa[8] = {q0.x, q0.y, q0.z, q0.w, q1.x, q1.y, q1.z, q1.w};
  float ga[8] = {g0.x, g0.y, g0.z, g0.w, g1.x, g1.y, g1.z, g1.w};
  float ba[8] = {b0.x, b0.y, b0.z, b0.w, b1.x, b1.y, b1.z, b1.w};
  f16x8 o;
#pragma unroll
  for (int j = 0; j < 8; ++j) {
    float mu = sa[j] * invN;
    float var = qa[j] * invN - mu * mu;
    float sc = rsqrtf(var + 1e-5f) * ga[j];
    float v = ((float)xv[j] - mu) * sc + ba[j];
    v = act ? tanhf(v) : (v >= 0.f ? v : 0.01f * v);
    o[j] = (_Float16)v;
  }
  *reinterpret_cast<f16x8*>(Y + i0) = o;
}

extern "C" void kernel_launch(void* const* d_in, const int* in_sizes, int n_in,
                              void* d_out, int out_size, void* d_ws, size_t ws_size,
                              hipStream_t stream) {
  (void)in_sizes; (void)n_in; (void)out_size; (void)ws_size;
  const float* x_user = (const float*)d_in[0];
  const float* x_item = (const float*)d_in[1];
  const int* ui_src = (const int*)d_in[2];
  const int* ui_dst = (const int*)d_in[3];
  const int* iu_src = (const int*)d_in[4];
  const int* iu_dst = (const int*)d_in[5];
  const float *Wp[4], *alp[4], *arp[4], *bp[4];
  for (int l = 0; l < 4; ++l) {
    Wp[l]  = (const float*)d_in[6 + 4 * l];
    alp[l] = (const float*)d_in[7 + 4 * l];
    arp[l] = (const float*)d_in[8 + 4 * l];
    bp[l]  = (const float*)d_in[9 + 4 * l];
  }
  const float* bng = (const float*)d_in[22];
  const float* bnb = (const float*)d_in[23];

  char* w = (char*)d_ws;
  auto alloc = [&](size_t bytes) -> void* {
    void* p = (void*)w;
    w += (bytes + 255) & ~(size_t)255;
    return p;
  };
  _Float16* XU16 = (_Float16*)alloc((size_t)NN * 128 * 2);
  _Float16* XI16 = (_Float16*)alloc((size_t)NN * 128 * 2);
  _Float16* H16U = (_Float16*)alloc((size_t)NN * HF * 2);
  _Float16* H16I = (_Float16*)alloc((size_t)NN * HF * 2);
  _Float16* Z0 = (_Float16*)alloc((size_t)NN * HF * 2);
  _Float16* Z1 = (_Float16*)alloc((size_t)NN * HF * 2);
  _Float16* RAW16U = (_Float16*)alloc((size_t)NN * HF * 2);
  _Float16* RAW16I = (_Float16*)alloc((size_t)NN * HF * 2);
  float* EL0 = (float*)alloc((size_t)NN * 4 * 4);
  float* ER0 = (float*)alloc((size_t)NN * 4 * 4);
  float* EL1 = (float*)alloc((size_t)NN * 4 * 4);
  float* ER1 = (float*)alloc((size_t)NN * 4 * 4);
  _Float16* WT = (_Float16*)alloc((size_t)8 * 65536 * 2);
  _Float16* WART = (_Float16*)alloc((size_t)8 * 4096 * 2);  // [8][16][256] fp16
  int* rp_ui = (int*)alloc((size_t)(NN + 1) * 4);
  int* rp_iu = (int*)alloc((size_t)(NN + 1) * 4);
  int* csrc_ui = (int*)alloc((size_t)NE * 4);
  int* csrc_iu = (int*)alloc((size_t)NE * 4);
  int* perm_ui = (int*)alloc((size_t)NN * 4);
  int* perm_iu = (int*)alloc((size_t)NN * 4);
  int* counts = (int*)alloc((size_t)4 * NN * 4);  // counts_ui | counts_iu | fill_ui | fill_iu
  int* bsum_ui = (int*)alloc((size_t)64 * 4);
  int* bsum_iu = (int*)alloc((size_t)64 * 4);
  int* degws = (int*)alloc((size_t)384 * 4);      // dh[128] | dofs[128] | dfill[128]
  float* stats = (float*)alloc((size_t)6 * 512 * 4);

  int* counts_ui = counts;
  int* counts_iu = counts + NN;
  int* fill_ui = counts + 2 * NN;
  int* fill_iu = counts + 3 * NN;
  int* dh = degws;
  int* dofs = degws + 128;
  int* dfill = degws + 256;

  hipMemsetAsync(counts, 0, (size_t)4 * NN * 4, stream);
  hipMemsetAsync(stats, 0, (size_t)6 * 512 * 4, stream);
  hipMemsetAsync(WART, 0, (size_t)8 * 4096 * 2, stream);
  hipMemsetAsync(degws, 0, (size_t)384 * 4, stream);

  // input conversion (one dispatch)
  int n4 = NN * 128 / 4;
  k_tofp16_2<<<(2 * n4 + 255) / 256, 256, 0, stream>>>(x_user, x_item, XU16, XI16, n4);

  // all weight transposes (one dispatch)
  TArgs ta;
  int cum = 0;
  for (int l = 0; l < 4; ++l) {
    int K = (l == 0) ? 128 : 256;
    for (int r = 0; r < 2; ++r) {
      int s = l * 2 + r;
      ta.W[s] = Wp[l] + (size_t)r * K * HF;
      ta.dst[s] = WT + (size_t)s * 65536;
      ta.K[s] = K;
      ta.cum[s] = cum;
      cum += K * 256;
    }
  }
  ta.cum[8] = cum;
  k_transpose_all<<<(cum + 255) / 256, 256, 0, stream>>>(ta);

  // all W.ar attn tables, fp16 padded (one dispatch)
  k_makeattn_all<<<(8 * 256 * 4 + 255) / 256, 256, 0, stream>>>(
      Wp[0], Wp[1], Wp[2], Wp[3], arp[0], arp[1], arp[2], arp[3], WART);

  // CSR build (both relations per dispatch)
  int egrid2 = (2 * NE + 255) / 256;
  int nscan = (NN + 1023) / 1024;
  k_hist2<<<egrid2, 256, 0, stream>>>(ui_dst, iu_dst, counts_ui, counts_iu);
  k_scan1_2<<<2 * nscan, 1024, 0, stream>>>(counts_ui, counts_iu, rp_ui, rp_iu, bsum_ui, bsum_iu, nscan);
  k_scan2_2<<<1, 128, 0, stream>>>(bsum_ui, bsum_iu, nscan);
  k_scan3_2<<<2 * nscan, 1024, 0, stream>>>(rp_ui, rp_iu, bsum_ui, bsum_iu, nscan);
  k_scatter2<<<egrid2, 256, 0, stream>>>(ui_src, ui_dst, iu_src, iu_dst, rp_ui, rp_iu,
                                         fill_ui, fill_iu, csrc_ui, csrc_iu);

  // degree-sorted permutations (both relations, LDS-privatized atomics)
  int ngrid2 = (2 * NN + 255) / 256;
  k_deghist2<<<ngrid2, 256, 0, stream>>>(rp_ui, rp_iu, dh);
  k_degscan<<<1, 128, 0, stream>>>(dh, dofs);
  k_permscatter2<<<ngrid2, 256, 0, stream>>>(rp_ui, rp_iu, dofs, dfill, perm_ui, perm_iu);

  int agrid8 = (NN + 7) / 8;
  int nrow = (NN + 63) / 64;
  float* out_user = (float*)d_out;
  float* out_item = (float*)d_out + (size_t)NN * HF;

  for (int l = 0; l < 4; ++l) {
    int K = (l == 0) ? 128 : 256;
    const _Float16* Au = (l == 0) ? XU16 : H16U;
    const _Float16* Ai = (l == 0) ? XI16 : H16I;

    // GEMM pair: Z0 = hu@W0 (+el0, +er1), Z1 = hi@W1 (+el1, +er0)
    GArgs ga;
    ga.A0 = Au; ga.A1 = Ai;
    ga.Wt0 = WT + (size_t)(l * 2 + 0) * 65536;
    ga.Wt1 = WT + (size_t)(l * 2 + 1) * 65536;
    ga.Z0 = Z0; ga.Z1 = Z1;
    ga.al0 = alp[l] + 0; ga.al1 = alp[l] + 256;
    ga.EL0 = EL0; ga.EL1 = EL1;
    ga.wart_s0 = WART + (size_t)(l * 2 + 1) * 4096;  // side0 (A=hu) -> er1 = hu.(W1.ar1)
    ga.wart_s1 = WART + (size_t)(l * 2 + 0) * 4096;  // side1 (A=hi) -> er0 = hi.(W0.ar0)
    ga.ER_s0 = ER1; ga.ER_s1 = ER0;
    ga.M = NN; ga.K = K;
    k_gemm5<<<2 * nrow, 256, 0, stream>>>(ga);

    // aggregation pair: u->i (dst items, Z0) and i->u (dst users, Z1)
    if (l < 3)
      k_agg3<_Float16><<<2 * agrid8, 256, 0, stream>>>(
          rp_ui, csrc_ui, perm_ui, EL0, ER0, Z0, bp[l] + 0, RAW16I,
          rp_iu, csrc_iu, perm_iu, EL1, ER1, Z1, bp[l] + 256, RAW16U);
    else
      k_agg3<float><<<2 * agrid8, 256, 0, stream>>>(
          rp_ui, csrc_ui, perm_ui, EL0, ER0, Z0, bp[l] + 0, out_item,
          rp_iu, csrc_iu, perm_iu, EL1, ER1, Z1, bp[l] + 256, out_user);

    if (l < 3) {
      int act = (l == 2) ? 1 : 0;
      float* su = stats + (size_t)(l * 2 + 0) * 512;
      float* si = stats + (size_t)(l * 2 + 1) * 512;
      k_bn_stats2<<<1024, 256, 0, stream>>>(RAW16U, RAW16I, su, su + 256, si, si + 256);
      k_bn_apply2<<<2 * (NN * HF / 8 / 256), 256, 0, stream>>>(
          RAW16U, RAW16I, su, su + 256, si, si + 256,
          bng + (size_t)(l * 2 + 0) * 256, bnb + (size_t)(l * 2 + 0) * 256,
          bng + (size_t)(l * 2 + 1) * 256, bnb + (size_t)(l * 2 + 1) * 256,
          H16U, H16I, act);
    }
  }
}